// Round 4
// baseline (5556.308 us; speedup 1.0000x reference)
//
#include <hip/hip_runtime.h>
#include <hip/hip_bf16.h>

// Problem constants (fixed by the reference)
#define NN   20000      // nodes
#define NE   320000     // edges
#define CC   256        // width
#define CA   512        // width_act

typedef __attribute__((ext_vector_type(4))) short s16x4;   // 4 bf16 (2 VGPRs)
typedef __attribute__((ext_vector_type(4))) float f32x4;   // MFMA accumulator

__device__ __forceinline__ unsigned short f2bf(float f) {
  unsigned int u = __float_as_uint(f);
  u += 0x7fff + ((u >> 16) & 1);          // RNE
  return (unsigned short)(u >> 16);
}
__device__ __forceinline__ float bf2f(unsigned short h) {
  return __uint_as_float(((unsigned int)h) << 16);
}

// K=16 bf16 MFMA: D[m,n] = A[m,:16]·B[n,:16] + C.
// Frag (A and B): elem j = M[lane&15][(lane>>4)*4 + j]. D: row=(lane>>4)*4+r, col=lane&15.
#if defined(__has_builtin)
#if __has_builtin(__builtin_amdgcn_mfma_f32_16x16x16bf16_1k)
#define HAVE_MFMA1K 1
#endif
#endif
__device__ __forceinline__ f32x4 MFMA16(s16x4 a, s16x4 b, f32x4 c) {
#ifdef HAVE_MFMA1K
  return __builtin_amdgcn_mfma_f32_16x16x16bf16_1k(a, b, c, 0, 0, 0);
#else
  f32x4 d;
  asm volatile("v_mfma_f32_16x16x16_bf16 %0, %1, %2, %3"
               : "=v"(d) : "v"(a), "v"(b), "v"(c));
  return d;
#endif
}

__device__ __forceinline__ s16x4 FR(const unsigned short* base, int f, int lane) {
  return *(const s16x4*)(base + (size_t)f * 256 + lane * 4);
}
__device__ __forceinline__ s16x4 pack4(f32x4 v) {
  s16x4 o;
  #pragma unroll
  for (int j = 0; j < 4; j++) o[j] = (short)f2bf(v[j]);
  return o;
}

// ---- repack weights [O][K] f32 -> frag-major bf16: frag f = kt*(O/16)+ot,
// frag[lane=(el,q)][j] = W[ot*16+el][kt*16+q*4+j], 512B per frag ----
__global__ void repack_kernel(const float* __restrict__ src,
                              unsigned short* __restrict__ dst,
                              int OT, int KT) {
  int g = blockIdx.x * 256 + threadIdx.x;
  if (g >= OT * KT * 64) return;
  int lane = g & 63, f = g >> 6;
  int kt = f / OT, ot = f - kt * OT;
  int el = lane & 15, q = lane >> 4;
  const float* s = src + (size_t)(ot * 16 + el) * (KT * 16) + kt * 16 + q * 4;
  unsigned short* d = dst + (size_t)f * 256 + lane * 4;
  d[0] = f2bf(s[0]); d[1] = f2bf(s[1]); d[2] = f2bf(s[2]); d[3] = f2bf(s[3]);
}

__global__ __launch_bounds__(256) void proj_kernel(
    const float* __restrict__ x, const float* __restrict__ w_src,
    const float* __restrict__ w_tgt, unsigned short* __restrict__ x0,
    unsigned short* __restrict__ x1) {
  __shared__ float xs[32 * 256];
  const int tid = threadIdx.x;
  const int row0 = blockIdx.x * 32;
  const float* w = blockIdx.y ? w_tgt : w_src;
  unsigned short* out = blockIdx.y ? x1 : x0;

  const float4* src = (const float4*)(x + (size_t)row0 * CC);
  float4* dstv = (float4*)xs;
  for (int i = tid; i < 2048; i += 256) dstv[i] = src[i];
  __syncthreads();

  const int c = tid;
  float acc[32];
  #pragma unroll
  for (int r = 0; r < 32; r++) acc[r] = 0.f;
  for (int k = 0; k < 256; k += 4) {
    float4 wv = *(const float4*)(w + (size_t)c * CC + k);
    #pragma unroll
    for (int r = 0; r < 32; r++) {
      float4 xv = *(const float4*)(&xs[r * 256 + k]);
      acc[r] += xv.x * wv.x + xv.y * wv.y + xv.z * wv.z + xv.w * wv.w;
    }
  }
  #pragma unroll
  for (int r = 0; r < 32; r++) out[(size_t)(row0 + r) * CC + c] = f2bf(acc[r]);
}

__global__ void deg_kernel(const int* __restrict__ ei, float* __restrict__ deg) {
  int e = blockIdx.x * blockDim.x + threadIdx.x;
  if (e >= NE) return;
  int k0 = ei[e], k1 = ei[NE + e];
  if (k0 != k1) atomicAdd(&deg[k1], 1.0f);
}

__global__ void finalize_kernel(const float* __restrict__ xx,
                                const float* __restrict__ deg,
                                const float* __restrict__ dp,
                                const float* __restrict__ x_res,
                                float* __restrict__ out) {
  int idx = blockIdx.x * blockDim.x + threadIdx.x;
  if (idx >= NN * CC) return;
  int n = idx >> 8, c = idx & 255;
  float d = fmaxf(deg[n], 1.0f);
  out[idx] = powf(d, dp[c]) * xx[idx] + x_res[idx];
}

// ---------------- fused all-register edge kernel ----------------
// Block = 4 waves = 2 e-tiles x 2 c-halves. Wave owns 16 edges (n=lane&15).
// Chain (A=weights as m, B=edges as n): every stage's D feeds the next
// stage's B-frag with zero data movement. One barrier (bias exchange).
__global__ __launch_bounds__(256, 4) void edge_fused(
    const unsigned short* __restrict__ x0g, const unsigned short* __restrict__ x1g,
    const float* __restrict__ z_rw, const int* __restrict__ ei,
    const unsigned short* __restrict__ Fpre,
    const unsigned short* __restrict__ Fg_p, const unsigned short* __restrict__ Fv_p,
    const unsigned short* __restrict__ Fp_p,
    const unsigned short* __restrict__ Fg_f, const unsigned short* __restrict__ Fv_f,
    const unsigned short* __restrict__ Fp_f,
    float* __restrict__ xx) {
  __shared__ unsigned short BLDS[2][16][64][4];   // 16KB bias frag exchange

  const int tid = threadIdx.x;
  const int lane = tid & 63;
  const int w = tid >> 6;
  const int el = lane & 15, q = lane >> 4;
  const int et1 = w >> 1;               // local e-tile 0/1
  const int chalf = w & 1;              // output-channel half
  const int ebase = (blockIdx.x * 2 + et1) * 16;
  const f32x4 zero4 = {0.f, 0.f, 0.f, 0.f};

  const int k0 = ei[ebase + el];
  const int k1 = ei[NE + ebase + el];

  // ---- perw pre-GEMM: D[c=256][e=16] from z frags ----
  float4 z0 = *(const float4*)(z_rw + (size_t)k0 * 16 + q * 4);
  float4 z1 = *(const float4*)(z_rw + (size_t)k1 * 16 + q * 4);
  s16x4 bz0, bz1;
  bz0[0] = (short)f2bf(z0.x); bz0[1] = (short)f2bf(z0.y);
  bz0[2] = (short)f2bf(z0.z); bz0[3] = (short)f2bf(z0.w);
  bz1[0] = (short)f2bf(z1.x); bz1[1] = (short)f2bf(z1.y);
  bz1[2] = (short)f2bf(z1.z); bz1[3] = (short)f2bf(z1.w);

  f32x4 pre[16];
  #pragma unroll
  for (int mt = 0; mt < 16; mt++) {
    f32x4 d = MFMA16(FR(Fpre, mt, lane), bz0, zero4);
    pre[mt] = MFMA16(FR(Fpre, 16 + mt, lane), bz1, d);
  }

  // ---- GroupNorm stats (per edge el, per head): cross-q shuffle reduce ----
  float mu[8], ri[8];
  #pragma unroll
  for (int h = 0; h < 8; h++) {
    float s1 = 0.f, s2 = 0.f;
    #pragma unroll
    for (int c = 0; c < 2; c++) {
      f32x4 v = pre[2 * h + c];
      #pragma unroll
      for (int j = 0; j < 4; j++) { s1 += v[j]; s2 += v[j] * v[j]; }
    }
    s1 += __shfl_xor(s1, 16); s1 += __shfl_xor(s1, 32);
    s2 += __shfl_xor(s2, 16); s2 += __shfl_xor(s2, 32);
    float m = s1 * (1.f / 32.f);
    float var = fmaxf(s2 * (1.f / 32.f) - m * m, 0.f);
    mu[h] = m; ri[h] = rsqrtf(var + 1e-5f);
  }
  s16x4 t[16];
  #pragma unroll
  for (int mt = 0; mt < 16; mt++) {
    int h = mt >> 1;
    f32x4 n;
    #pragma unroll
    for (int j = 0; j < 4; j++) n[j] = (pre[mt][j] - mu[h]) * ri[h];
    t[mt] = pack4(n);
  }

  // ---- perw gate/value + post-GEMM (this wave's 8 c-tiles) ----
  f32x4 acc[8];
  #pragma unroll
  for (int c8 = 0; c8 < 8; c8++) acc[c8] = zero4;
  #pragma unroll
  for (int h = 0; h < 8; h++) {
    #pragma unroll
    for (int ot = 0; ot < 4; ot++) {
      int kpc = h * 4 + ot;
      f32x4 g = MFMA16(FR(Fg_p, kpc, lane), t[2 * h], zero4);
      g = MFMA16(FR(Fg_p, 32 + kpc, lane), t[2 * h + 1], g);
      f32x4 v = MFMA16(FR(Fv_p, kpc, lane), t[2 * h], zero4);
      v = MFMA16(FR(Fv_p, 32 + kpc, lane), t[2 * h + 1], v);
      f32x4 uf;
      #pragma unroll
      for (int j = 0; j < 4; j++) uf[j] = fmaxf(g[j], 0.f) * v[j];
      s16x4 u = pack4(uf);
      #pragma unroll
      for (int c8 = 0; c8 < 8; c8++)
        acc[c8] = MFMA16(FR(Fp_p, kpc * 16 + chalf * 8 + c8, lane), u, acc[c8]);
    }
  }

  // ---- bias exchange (only cross-wave dependency) ----
  #pragma unroll
  for (int c8 = 0; c8 < 8; c8++)
    *(s16x4*)&BLDS[et1][chalf * 8 + c8][lane][0] = pack4(acc[c8]);
  __syncthreads();

  // ---- ffn msg = x0[k0]+x1[k1]: stats from f32 sums, store bf16 ----
  s16x4 tv[16];
  {
    float s1[8], s2[8];
    #pragma unroll
    for (int h = 0; h < 8; h++) { s1[h] = 0.f; s2[h] = 0.f; }
    #pragma unroll
    for (int mt = 0; mt < 16; mt++) {
      s16x4 a = *(const s16x4*)(x0g + (size_t)k0 * 256 + mt * 16 + q * 4);
      s16x4 b = *(const s16x4*)(x1g + (size_t)k1 * 256 + mt * 16 + q * 4);
      f32x4 f;
      #pragma unroll
      for (int j = 0; j < 4; j++) {
        f[j] = bf2f((unsigned short)a[j]) + bf2f((unsigned short)b[j]);
        s1[mt >> 1] += f[j]; s2[mt >> 1] += f[j] * f[j];
      }
      tv[mt] = pack4(f);   // raw msg (normalized in place below)
    }
    #pragma unroll
    for (int h = 0; h < 8; h++) {
      float a = s1[h], b = s2[h];
      a += __shfl_xor(a, 16); a += __shfl_xor(a, 32);
      b += __shfl_xor(b, 16); b += __shfl_xor(b, 32);
      float m = a * (1.f / 32.f);
      float var = fmaxf(b * (1.f / 32.f) - m * m, 0.f);
      mu[h] = m; ri[h] = rsqrtf(var + 1e-5f);
    }
    #pragma unroll
    for (int mt = 0; mt < 16; mt++) {
      int h = mt >> 1;
      f32x4 n;
      #pragma unroll
      for (int j = 0; j < 4; j++)
        n[j] = (bf2f((unsigned short)tv[mt][j]) - mu[h]) * ri[h];
      tv[mt] = pack4(n);
    }
  }

  // ---- ffn gate(+bias)/value + post-GEMM ----
  #pragma unroll
  for (int c8 = 0; c8 < 8; c8++) acc[c8] = zero4;
  #pragma unroll
  for (int h = 0; h < 8; h++) {
    s16x4 b0 = *(const s16x4*)&BLDS[et1][2 * h][lane][0];
    s16x4 b1 = *(const s16x4*)&BLDS[et1][2 * h + 1][lane][0];
    s16x4 tg0, tg1;
    #pragma unroll
    for (int j = 0; j < 4; j++) {
      tg0[j] = (short)f2bf(bf2f((unsigned short)tv[2 * h][j]) +
                           bf2f((unsigned short)b0[j]));
      tg1[j] = (short)f2bf(bf2f((unsigned short)tv[2 * h + 1][j]) +
                           bf2f((unsigned short)b1[j]));
    }
    #pragma unroll
    for (int ot = 0; ot < 4; ot++) {
      int kpc = h * 4 + ot;
      f32x4 g = MFMA16(FR(Fg_f, kpc, lane), tg0, zero4);
      g = MFMA16(FR(Fg_f, 32 + kpc, lane), tg1, g);
      f32x4 v = MFMA16(FR(Fv_f, kpc, lane), tv[2 * h], zero4);
      v = MFMA16(FR(Fv_f, 32 + kpc, lane), tv[2 * h + 1], v);
      f32x4 uf;
      #pragma unroll
      for (int j = 0; j < 4; j++) uf[j] = fmaxf(g[j], 0.f) * v[j];
      s16x4 u = pack4(uf);
      #pragma unroll
      for (int c8 = 0; c8 < 8; c8++)
        acc[c8] = MFMA16(FR(Fp_f, kpc * 16 + chalf * 8 + c8, lane), u, acc[c8]);
    }
  }

  // ---- masked atomic scatter ----
  if (k0 != k1) {
    float* dst = xx + (size_t)k1 * 256 + chalf * 128 + q * 4;
    #pragma unroll
    for (int c8 = 0; c8 < 8; c8++) {
      atomicAdd(dst + c8 * 16 + 0, acc[c8][0]);
      atomicAdd(dst + c8 * 16 + 1, acc[c8][1]);
      atomicAdd(dst + c8 * 16 + 2, acc[c8][2]);
      atomicAdd(dst + c8 * 16 + 3, acc[c8][3]);
    }
  }
}

extern "C" void kernel_launch(void* const* d_in, const int* in_sizes, int n_in,
                              void* d_out, int out_size, void* d_ws, size_t ws_size,
                              hipStream_t stream) {
  (void)in_sizes; (void)n_in; (void)out_size; (void)ws_size;
  const float* x        = (const float*)d_in[0];
  const float* x_res    = (const float*)d_in[1];
  const float* z_rw     = (const float*)d_in[2];
  const int*   ei       = (const int*)d_in[3];
  const float* w_src    = (const float*)d_in[4];
  const float* w_tgt    = (const float*)d_in[5];
  const float* w_pre    = (const float*)d_in[6];
  const float* w_gate_p = (const float*)d_in[7];
  const float* w_val_p  = (const float*)d_in[8];
  const float* w_post_p = (const float*)d_in[9];
  const float* w_gate_f = (const float*)d_in[10];
  const float* w_val_f  = (const float*)d_in[11];
  const float* w_post_f = (const float*)d_in[12];
  const float* dparam   = (const float*)d_in[13];
  float* out = (float*)d_out;

  // workspace layout
  unsigned short* x0 = (unsigned short*)d_ws;
  unsigned short* x1 = x0 + (size_t)NN * CC;
  float* xx  = (float*)(x1 + (size_t)NN * CC);
  float* deg = xx + (size_t)NN * CC;
  unsigned short* Fpre = (unsigned short*)(deg + NN);   // 32 frags
  unsigned short* Fg_p = Fpre + 8192;                   // 64 frags
  unsigned short* Fv_p = Fg_p + 16384;
  unsigned short* Fp_p = Fv_p + 16384;                  // 512 frags
  unsigned short* Fg_f = Fp_p + 131072;
  unsigned short* Fv_f = Fg_f + 16384;
  unsigned short* Fp_f = Fv_f + 16384;

  hipMemsetAsync(xx, 0, ((size_t)NN * CC + NN) * sizeof(float), stream);

  repack_kernel<<<8, 256, 0, stream>>>(w_pre, Fpre, 16, 2);
  repack_kernel<<<16, 256, 0, stream>>>(w_gate_p, Fg_p, 32, 2);
  repack_kernel<<<16, 256, 0, stream>>>(w_val_p, Fv_p, 32, 2);
  repack_kernel<<<128, 256, 0, stream>>>(w_post_p, Fp_p, 16, 32);
  repack_kernel<<<16, 256, 0, stream>>>(w_gate_f, Fg_f, 32, 2);
  repack_kernel<<<16, 256, 0, stream>>>(w_val_f, Fv_f, 32, 2);
  repack_kernel<<<128, 256, 0, stream>>>(w_post_f, Fp_f, 16, 32);

  proj_kernel<<<dim3(NN / 32, 2), 256, 0, stream>>>(x, w_src, w_tgt, x0, x1);
  deg_kernel<<<(NE + 255) / 256, 256, 0, stream>>>(ei, deg);
  edge_fused<<<NE / 32, 256, 0, stream>>>(x0, x1, z_rw, ei,
                                          Fpre, Fg_p, Fv_p, Fp_p,
                                          Fg_f, Fv_f, Fp_f, xx);
  finalize_kernel<<<(NN * CC + 255) / 256, 256, 0, stream>>>(xx, deg, dparam,
                                                             x_res, out);
}

// Round 6
// 3283.224 us; speedup vs baseline: 1.6923x; 1.6923x over previous
//
#include <hip/hip_runtime.h>
#include <hip/hip_bf16.h>

// Problem constants (fixed by the reference)
#define NN   20000      // nodes
#define NE   320000     // edges
#define CC   256        // width
#define CA   512        // width_act

typedef __attribute__((ext_vector_type(4))) short s16x4;   // 4 bf16 (2 VGPRs)
typedef __attribute__((ext_vector_type(4))) float f32x4;   // MFMA accumulator

__device__ __forceinline__ unsigned short f2bf(float f) {
  unsigned int u = __float_as_uint(f);
  u += 0x7fff + ((u >> 16) & 1);          // RNE
  return (unsigned short)(u >> 16);
}
__device__ __forceinline__ float bf2f(unsigned short h) {
  return __uint_as_float(((unsigned int)h) << 16);
}

// K=16 bf16 MFMA: operand frag (A or B): elem j = M[lane&15][(lane>>4)*4+j].
// D: col = lane&15 (N), row = (lane>>4)*4 + reg (M).  (validated by round 4)
#if defined(__has_builtin)
#if __has_builtin(__builtin_amdgcn_mfma_f32_16x16x16bf16_1k)
#define HAVE_MFMA1K 1
#endif
#endif
__device__ __forceinline__ f32x4 MFMA16(s16x4 a, s16x4 b, f32x4 c) {
#ifdef HAVE_MFMA1K
  return __builtin_amdgcn_mfma_f32_16x16x16bf16_1k(a, b, c, 0, 0, 0);
#else
  f32x4 d;
  asm volatile("v_mfma_f32_16x16x16_bf16 %0, %1, %2, %3"
               : "=&v"(d) : "v"(a), "v"(b), "v"(c));
  return d;
#endif
}

__device__ __forceinline__ s16x4 FR(const unsigned short* base, int f, int lane) {
  return *(const s16x4*)(base + (size_t)f * 256 + lane * 4);
}
// scalar pack (round-4 proven; no inline asm)
__device__ __forceinline__ s16x4 pack4(f32x4 v) {
  s16x4 o;
  #pragma unroll
  for (int j = 0; j < 4; j++) o[j] = (short)f2bf(v[j]);
  return o;
}
__device__ __forceinline__ f32x4 up4(s16x4 v) {
  f32x4 o;
  #pragma unroll
  for (int j = 0; j < 4; j++) o[j] = bf2f((unsigned short)v[j]);
  return o;
}

// ---- repack weights [O][K] f32 -> frag-major bf16: frag f = kt*(O/16)+ot,
// frag[lane=(el,q)][j] = W[ot*16+el][kt*16+q*4+j], 512B per frag ----
__global__ void repack_kernel(const float* __restrict__ src,
                              unsigned short* __restrict__ dst,
                              int OT, int KT) {
  int g = blockIdx.x * 256 + threadIdx.x;
  if (g >= OT * KT * 64) return;
  int lane = g & 63, f = g >> 6;
  int kt = f / OT, ot = f - kt * OT;
  int el = lane & 15, q = lane >> 4;
  const float* s = src + (size_t)(ot * 16 + el) * (KT * 16) + kt * 16 + q * 4;
  unsigned short* d = dst + (size_t)f * 256 + lane * 4;
  d[0] = f2bf(s[0]); d[1] = f2bf(s[1]); d[2] = f2bf(s[2]); d[3] = f2bf(s[3]);
}

__global__ __launch_bounds__(256) void proj_kernel(
    const float* __restrict__ x, const float* __restrict__ w_src,
    const float* __restrict__ w_tgt, unsigned short* __restrict__ x0,
    unsigned short* __restrict__ x1) {
  __shared__ float xs[32 * 256];
  const int tid = threadIdx.x;
  const int row0 = blockIdx.x * 32;
  const float* w = blockIdx.y ? w_tgt : w_src;
  unsigned short* out = blockIdx.y ? x1 : x0;

  const float4* src = (const float4*)(x + (size_t)row0 * CC);
  float4* dstv = (float4*)xs;
  for (int i = tid; i < 2048; i += 256) dstv[i] = src[i];
  __syncthreads();

  const int c = tid;
  float acc[32];
  #pragma unroll
  for (int r = 0; r < 32; r++) acc[r] = 0.f;
  for (int k = 0; k < 256; k += 4) {
    float4 wv = *(const float4*)(w + (size_t)c * CC + k);
    #pragma unroll
    for (int r = 0; r < 32; r++) {
      float4 xv = *(const float4*)(&xs[r * 256 + k]);
      acc[r] += xv.x * wv.x + xv.y * wv.y + xv.z * wv.z + xv.w * wv.w;
    }
  }
  #pragma unroll
  for (int r = 0; r < 32; r++) out[(size_t)(row0 + r) * CC + c] = f2bf(acc[r]);
}

__global__ void deg_kernel(const int* __restrict__ ei, float* __restrict__ deg) {
  int e = blockIdx.x * blockDim.x + threadIdx.x;
  if (e >= NE) return;
  int k0 = ei[e], k1 = ei[NE + e];
  if (k0 != k1) atomicAdd(&deg[k1], 1.0f);
}

__global__ void finalize_kernel(const float* __restrict__ xx,
                                const float* __restrict__ deg,
                                const float* __restrict__ dp,
                                const float* __restrict__ x_res,
                                float* __restrict__ out) {
  int idx = blockIdx.x * blockDim.x + threadIdx.x;
  if (idx >= NN * CC) return;
  int n = idx >> 8, c = idx & 255;
  float d = fmaxf(deg[n], 1.0f);
  out[idx] = powf(d, dp[c]) * xx[idx] + x_res[idx];
}

// ---------------- fused all-register edge kernel ----------------
// Block = 4 waves = 2 tile-pairs x 2 c-halves. Wave: 2 e-tiles (32 edges),
// half the post output channels. One barrier (bias exchange). Final
// post-GEMM uses A=u so D cols = out-channels -> full-64B-line atomics.
__global__ __launch_bounds__(256, 3) void edge_fused(
    const unsigned short* __restrict__ x0g, const unsigned short* __restrict__ x1g,
    const float* __restrict__ z_rw, const int* __restrict__ ei,
    const unsigned short* __restrict__ Fpre,
    const unsigned short* __restrict__ Fg_p, const unsigned short* __restrict__ Fv_p,
    const unsigned short* __restrict__ Fp_p,
    const unsigned short* __restrict__ Fg_f, const unsigned short* __restrict__ Fv_f,
    const unsigned short* __restrict__ Fp_f,
    float* __restrict__ xx) {
  __shared__ s16x4 BLDS[4][16][64];     // 32KB bias frag exchange
  __shared__ int K0s[64], K1s[64];

  const int tid = threadIdx.x;
  const int lane = tid & 63;
  const int w = tid >> 6;
  const int el = lane & 15, q = lane >> 4;
  const int chalf = w & 1;              // post output-channel half
  const int tp = w >> 1;                // tile-pair 0/1
  const int ebase = blockIdx.x * 64 + tp * 32;
  const f32x4 zero4 = {0.f, 0.f, 0.f, 0.f};

  int k0[2], k1[2];
  #pragma unroll
  for (int t = 0; t < 2; t++) {
    k0[t] = ei[ebase + t * 16 + el];
    k1[t] = ei[NE + ebase + t * 16 + el];
  }
  if (chalf == 0 && q == 0) {
    #pragma unroll
    for (int t = 0; t < 2; t++) {
      K0s[tp * 32 + t * 16 + el] = k0[t];
      K1s[tp * 32 + t * 16 + el] = k1[t];
    }
  }

  // z B-frags: bz0 = z_rw[k0] (k 0..15), bz1 = z_rw[k1] (k 16..31)
  s16x4 bz0[2], bz1[2];
  #pragma unroll
  for (int t = 0; t < 2; t++) {
    float4 a = *(const float4*)(z_rw + (size_t)k0[t] * 16 + q * 4);
    float4 b = *(const float4*)(z_rw + (size_t)k1[t] * 16 + q * 4);
    bz0[t][0] = (short)f2bf(a.x); bz0[t][1] = (short)f2bf(a.y);
    bz0[t][2] = (short)f2bf(a.z); bz0[t][3] = (short)f2bf(a.w);
    bz1[t][0] = (short)f2bf(b.x); bz1[t][1] = (short)f2bf(b.y);
    bz1[t][2] = (short)f2bf(b.z); bz1[t][3] = (short)f2bf(b.w);
  }

  f32x4 acc[2][8];
  #pragma unroll
  for (int t = 0; t < 2; t++)
    #pragma unroll
    for (int c8 = 0; c8 < 8; c8++) acc[t][c8] = zero4;

  // ================= perw block (per-h fused) =================
  #pragma unroll
  for (int h = 0; h < 8; h++) {
    // pre-GEMM for this head's 2 m-tiles
    f32x4 pr[2][2];
    #pragma unroll
    for (int mt2 = 0; mt2 < 2; mt2++) {
      int mt = 2 * h + mt2;
      s16x4 fa0 = FR(Fpre, mt, lane);
      s16x4 fa1 = FR(Fpre, 16 + mt, lane);
      #pragma unroll
      for (int t = 0; t < 2; t++) {
        f32x4 d = MFMA16(fa0, bz0[t], zero4);
        pr[t][mt2] = MFMA16(fa1, bz1[t], d);
      }
    }
    // GroupNorm (32 ch of head h) + pack
    s16x4 t16[2][2];
    #pragma unroll
    for (int t = 0; t < 2; t++) {
      float s1 = 0.f, s2 = 0.f;
      #pragma unroll
      for (int mt2 = 0; mt2 < 2; mt2++)
        #pragma unroll
        for (int j = 0; j < 4; j++) {
          float v = pr[t][mt2][j];
          s1 += v; s2 += v * v;
        }
      s1 += __shfl_xor(s1, 16); s1 += __shfl_xor(s1, 32);
      s2 += __shfl_xor(s2, 16); s2 += __shfl_xor(s2, 32);
      float mu = s1 * (1.f / 32.f);
      float var = fmaxf(s2 * (1.f / 32.f) - mu * mu, 0.f);
      float ri = rsqrtf(var + 1e-5f);
      #pragma unroll
      for (int mt2 = 0; mt2 < 2; mt2++) {
        f32x4 n;
        #pragma unroll
        for (int j = 0; j < 4; j++) n[j] = (pr[t][mt2][j] - mu) * ri;
        t16[t][mt2] = pack4(n);
      }
    }
    // grouped gate/value + post accumulate (A=W: D rows=out-ch)
    #pragma unroll
    for (int ot = 0; ot < 4; ot++) {
      int kpc = h * 4 + ot;
      s16x4 fg0 = FR(Fg_p, kpc, lane), fg1 = FR(Fg_p, 32 + kpc, lane);
      s16x4 fv0 = FR(Fv_p, kpc, lane), fv1 = FR(Fv_p, 32 + kpc, lane);
      s16x4 u[2];
      #pragma unroll
      for (int t = 0; t < 2; t++) {
        f32x4 g = MFMA16(fg0, t16[t][0], zero4);
        g = MFMA16(fg1, t16[t][1], g);
        f32x4 v = MFMA16(fv0, t16[t][0], zero4);
        v = MFMA16(fv1, t16[t][1], v);
        f32x4 uf;
        #pragma unroll
        for (int j = 0; j < 4; j++) uf[j] = fmaxf(g[j], 0.f) * v[j];
        u[t] = pack4(uf);
      }
      #pragma unroll
      for (int c8 = 0; c8 < 8; c8++) {
        s16x4 fp = FR(Fp_p, kpc * 16 + chalf * 8 + c8, lane);
        #pragma unroll
        for (int t = 0; t < 2; t++)
          acc[t][c8] = MFMA16(fp, u[t], acc[t][c8]);
      }
    }
  }

  // ---- bias exchange (only barrier) ----
  #pragma unroll
  for (int t = 0; t < 2; t++)
    #pragma unroll
    for (int c8 = 0; c8 < 8; c8++)
      BLDS[tp * 2 + t][chalf * 8 + c8][lane] = pack4(acc[t][c8]);
  __syncthreads();

  // ================= ffn block (per-h fused) =================
  #pragma unroll
  for (int t = 0; t < 2; t++)
    #pragma unroll
    for (int c8 = 0; c8 < 8; c8++) acc[t][c8] = zero4;

  #pragma unroll
  for (int h = 0; h < 8; h++) {
    f32x4 nm[2][2];
    s16x4 tv16[2][2], tg16[2][2];
    #pragma unroll
    for (int t = 0; t < 2; t++) {
      f32x4 m[2];
      #pragma unroll
      for (int mt2 = 0; mt2 < 2; mt2++) {
        int mt = 2 * h + mt2;
        s16x4 a = *(const s16x4*)(x0g + (size_t)k0[t] * 256 + mt * 16 + q * 4);
        s16x4 b = *(const s16x4*)(x1g + (size_t)k1[t] * 256 + mt * 16 + q * 4);
        #pragma unroll
        for (int j = 0; j < 4; j++)
          m[mt2][j] = bf2f((unsigned short)a[j]) + bf2f((unsigned short)b[j]);
      }
      float s1 = 0.f, s2 = 0.f;
      #pragma unroll
      for (int mt2 = 0; mt2 < 2; mt2++)
        #pragma unroll
        for (int j = 0; j < 4; j++) { s1 += m[mt2][j]; s2 += m[mt2][j] * m[mt2][j]; }
      s1 += __shfl_xor(s1, 16); s1 += __shfl_xor(s1, 32);
      s2 += __shfl_xor(s2, 16); s2 += __shfl_xor(s2, 32);
      float mu = s1 * (1.f / 32.f);
      float var = fmaxf(s2 * (1.f / 32.f) - mu * mu, 0.f);
      float ri = rsqrtf(var + 1e-5f);
      s16x4 b0 = BLDS[tp * 2 + t][2 * h][lane];
      s16x4 b1 = BLDS[tp * 2 + t][2 * h + 1][lane];
      f32x4 bb0 = up4(b0), bb1 = up4(b1);
      #pragma unroll
      for (int mt2 = 0; mt2 < 2; mt2++) {
        #pragma unroll
        for (int j = 0; j < 4; j++) nm[t][mt2][j] = (m[mt2][j] - mu) * ri;
        tv16[t][mt2] = pack4(nm[t][mt2]);
      }
      f32x4 g0, g1;
      #pragma unroll
      for (int j = 0; j < 4; j++) {
        g0[j] = nm[t][0][j] + bb0[j];
        g1[j] = nm[t][1][j] + bb1[j];
      }
      tg16[t][0] = pack4(g0);
      tg16[t][1] = pack4(g1);
    }
    #pragma unroll
    for (int ot = 0; ot < 4; ot++) {
      int kpc = h * 4 + ot;
      s16x4 fg0 = FR(Fg_f, kpc, lane), fg1 = FR(Fg_f, 32 + kpc, lane);
      s16x4 fv0 = FR(Fv_f, kpc, lane), fv1 = FR(Fv_f, 32 + kpc, lane);
      s16x4 u[2];
      #pragma unroll
      for (int t = 0; t < 2; t++) {
        f32x4 g = MFMA16(fg0, tg16[t][0], zero4);
        g = MFMA16(fg1, tg16[t][1], g);
        f32x4 v = MFMA16(fv0, tv16[t][0], zero4);
        v = MFMA16(fv1, tv16[t][1], v);
        f32x4 uf;
        #pragma unroll
        for (int j = 0; j < 4; j++) uf[j] = fmaxf(g[j], 0.f) * v[j];
        u[t] = pack4(uf);
      }
      #pragma unroll
      for (int c8 = 0; c8 < 8; c8++) {
        s16x4 fb = FR(Fp_f, kpc * 16 + chalf * 8 + c8, lane);
        #pragma unroll
        for (int t = 0; t < 2; t++)
          acc[t][c8] = MFMA16(u[t], fb, acc[t][c8]);   // A=u: D cols=out-ch
      }
    }
  }

  // ---- masked scatter: 16 lanes cover a full 64B line per instruction ----
  #pragma unroll
  for (int t = 0; t < 2; t++) {
    #pragma unroll
    for (int r = 0; r < 4; r++) {
      int eL = tp * 32 + t * 16 + q * 4 + r;
      int kk0 = K0s[eL], kk1 = K1s[eL];
      if (kk0 != kk1) {
        float* dst = xx + (size_t)kk1 * 256 + (chalf * 8) * 16 + el;
        #pragma unroll
        for (int c8 = 0; c8 < 8; c8++)
          atomicAdd(dst + c8 * 16, acc[t][c8][r]);
      }
    }
  }
}

extern "C" void kernel_launch(void* const* d_in, const int* in_sizes, int n_in,
                              void* d_out, int out_size, void* d_ws, size_t ws_size,
                              hipStream_t stream) {
  (void)in_sizes; (void)n_in; (void)out_size; (void)ws_size;
  const float* x        = (const float*)d_in[0];
  const float* x_res    = (const float*)d_in[1];
  const float* z_rw     = (const float*)d_in[2];
  const int*   ei       = (const int*)d_in[3];
  const float* w_src    = (const float*)d_in[4];
  const float* w_tgt    = (const float*)d_in[5];
  const float* w_pre    = (const float*)d_in[6];
  const float* w_gate_p = (const float*)d_in[7];
  const float* w_val_p  = (const float*)d_in[8];
  const float* w_post_p = (const float*)d_in[9];
  const float* w_gate_f = (const float*)d_in[10];
  const float* w_val_f  = (const float*)d_in[11];
  const float* w_post_f = (const float*)d_in[12];
  const float* dparam   = (const float*)d_in[13];
  float* out = (float*)d_out;

  // workspace layout
  unsigned short* x0 = (unsigned short*)d_ws;
  unsigned short* x1 = x0 + (size_t)NN * CC;
  float* xx  = (float*)(x1 + (size_t)NN * CC);
  float* deg = xx + (size_t)NN * CC;
  unsigned short* Fpre = (unsigned short*)(deg + NN);   // 32 frags
  unsigned short* Fg_p = Fpre + 8192;                   // 64 frags
  unsigned short* Fv_p = Fg_p + 16384;
  unsigned short* Fp_p = Fv_p + 16384;                  // 512 frags
  unsigned short* Fg_f = Fp_p + 131072;
  unsigned short* Fv_f = Fg_f + 16384;
  unsigned short* Fp_f = Fv_f + 16384;

  hipMemsetAsync(xx, 0, ((size_t)NN * CC + NN) * sizeof(float), stream);

  repack_kernel<<<8, 256, 0, stream>>>(w_pre, Fpre, 16, 2);
  repack_kernel<<<16, 256, 0, stream>>>(w_gate_p, Fg_p, 32, 2);
  repack_kernel<<<16, 256, 0, stream>>>(w_val_p, Fv_p, 32, 2);
  repack_kernel<<<128, 256, 0, stream>>>(w_post_p, Fp_p, 16, 32);
  repack_kernel<<<16, 256, 0, stream>>>(w_gate_f, Fg_f, 32, 2);
  repack_kernel<<<16, 256, 0, stream>>>(w_val_f, Fv_f, 32, 2);
  repack_kernel<<<128, 256, 0, stream>>>(w_post_f, Fp_f, 16, 32);

  proj_kernel<<<dim3(NN / 32, 2), 256, 0, stream>>>(x, w_src, w_tgt, x0, x1);
  deg_kernel<<<(NE + 255) / 256, 256, 0, stream>>>(ei, deg);
  edge_fused<<<NE / 64, 256, 0, stream>>>(x0, x1, z_rw, ei,
                                          Fpre, Fg_p, Fv_p, Fp_p,
                                          Fg_f, Fv_f, Fp_f, xx);
  finalize_kernel<<<(NN * CC + 255) / 256, 256, 0, stream>>>(xx, deg, dparam,
                                                             x_res, out);
}

// Round 7
// 3128.301 us; speedup vs baseline: 1.7761x; 1.0495x over previous
//
#include <hip/hip_runtime.h>
#include <hip/hip_bf16.h>

// Problem constants (fixed by the reference)
#define NN   20000      // nodes
#define NE   320000     // edges
#define CC   256        // width
#define CA   512        // width_act

typedef __attribute__((ext_vector_type(4))) short s16x4;   // 4 bf16 (2 VGPRs)
typedef __attribute__((ext_vector_type(4))) float f32x4;   // MFMA accumulator

__device__ __forceinline__ unsigned short f2bf(float f) {
  unsigned int u = __float_as_uint(f);
  u += 0x7fff + ((u >> 16) & 1);          // RNE
  return (unsigned short)(u >> 16);
}
__device__ __forceinline__ float bf2f(unsigned short h) {
  return __uint_as_float(((unsigned int)h) << 16);
}

// K=16 bf16 MFMA: operand frag (A or B): elem j = M[row=lane&15][k=(lane>>4)*4+j].
// D: col = lane&15 (N), row = (lane>>4)*4 + reg (M).  (validated rounds 4/6)
#if defined(__has_builtin)
#if __has_builtin(__builtin_amdgcn_mfma_f32_16x16x16bf16_1k)
#define HAVE_MFMA1K 1
#endif
#endif
__device__ __forceinline__ f32x4 MFMA16(s16x4 a, s16x4 b, f32x4 c) {
#ifdef HAVE_MFMA1K
  return __builtin_amdgcn_mfma_f32_16x16x16bf16_1k(a, b, c, 0, 0, 0);
#else
  f32x4 d;
  asm volatile("v_mfma_f32_16x16x16_bf16 %0, %1, %2, %3"
               : "=&v"(d) : "v"(a), "v"(b), "v"(c));
  return d;
#endif
}

__device__ __forceinline__ s16x4 FR(const unsigned short* base, int f, int lane) {
  return *(const s16x4*)(base + (size_t)f * 256 + lane * 4);
}
__device__ __forceinline__ s16x4 ntload4(const unsigned short* p) {
  return __builtin_nontemporal_load((const s16x4*)p);
}
__device__ __forceinline__ s16x4 pack4(f32x4 v) {
  s16x4 o;
  #pragma unroll
  for (int j = 0; j < 4; j++) o[j] = (short)f2bf(v[j]);
  return o;
}
__device__ __forceinline__ f32x4 up4(s16x4 v) {
  f32x4 o;
  #pragma unroll
  for (int j = 0; j < 4; j++) o[j] = bf2f((unsigned short)v[j]);
  return o;
}

// ---- repack weights [O][K] f32 -> frag-major bf16: frag f = kt*(O/16)+ot,
// frag[lane=(el,q)][j] = W[ot*16+el][kt*16+q*4+j], 512B per frag ----
__global__ void repack_kernel(const float* __restrict__ src,
                              unsigned short* __restrict__ dst,
                              int OT, int KT) {
  int g = blockIdx.x * 256 + threadIdx.x;
  if (g >= OT * KT * 64) return;
  int lane = g & 63, f = g >> 6;
  int kt = f / OT, ot = f - kt * OT;
  int el = lane & 15, q = lane >> 4;
  const float* s = src + (size_t)(ot * 16 + el) * (KT * 16) + kt * 16 + q * 4;
  unsigned short* d = dst + (size_t)f * 256 + lane * 4;
  d[0] = f2bf(s[0]); d[1] = f2bf(s[1]); d[2] = f2bf(s[2]); d[3] = f2bf(s[3]);
}

__global__ __launch_bounds__(256) void proj_kernel(
    const float* __restrict__ x, const float* __restrict__ w_src,
    const float* __restrict__ w_tgt, unsigned short* __restrict__ x0,
    unsigned short* __restrict__ x1) {
  __shared__ float xs[32 * 256];
  const int tid = threadIdx.x;
  const int row0 = blockIdx.x * 32;
  const float* w = blockIdx.y ? w_tgt : w_src;
  unsigned short* out = blockIdx.y ? x1 : x0;

  const float4* src = (const float4*)(x + (size_t)row0 * CC);
  float4* dstv = (float4*)xs;
  for (int i = tid; i < 2048; i += 256) dstv[i] = src[i];
  __syncthreads();

  const int c = tid;
  float acc[32];
  #pragma unroll
  for (int r = 0; r < 32; r++) acc[r] = 0.f;
  for (int k = 0; k < 256; k += 4) {
    float4 wv = *(const float4*)(w + (size_t)c * CC + k);
    #pragma unroll
    for (int r = 0; r < 32; r++) {
      float4 xv = *(const float4*)(&xs[r * 256 + k]);
      acc[r] += xv.x * wv.x + xv.y * wv.y + xv.z * wv.z + xv.w * wv.w;
    }
  }
  #pragma unroll
  for (int r = 0; r < 32; r++) out[(size_t)(row0 + r) * CC + c] = f2bf(acc[r]);
}

__global__ void deg_int_kernel(const int* __restrict__ ei, int* __restrict__ degi) {
  int e = blockIdx.x * blockDim.x + threadIdx.x;
  if (e >= NE) return;
  int k0 = ei[e], k1 = ei[NE + e];
  if (k0 != k1) atomicAdd(&degi[k1], 1);
}

// exclusive prefix sum over degi[NN] -> starts[NN+1]; 1 block of 64 lanes
__global__ __launch_bounds__(64) void prefix_kernel(const int* __restrict__ degi,
                                                    int* __restrict__ starts) {
  int lane = threadIdx.x;
  int runoff = 0;
  for (int base = 0; base < NN; base += 64) {
    int v = (base + lane < NN) ? degi[base + lane] : 0;
    int s = v;
    #pragma unroll
    for (int o = 1; o < 64; o <<= 1) {
      int x = __shfl_up(s, o);
      if (lane >= o) s += x;
    }
    if (base + lane < NN) starts[base + lane] = runoff + s - v;
    runoff += __shfl(s, 63);
  }
  if (lane == 0) starts[NN] = runoff;
}

__global__ void fill_kernel(const int* __restrict__ ei, const int* __restrict__ starts,
                            int* __restrict__ cursor, int* __restrict__ elist) {
  int e = blockIdx.x * blockDim.x + threadIdx.x;
  if (e >= NE) return;
  int k0 = ei[e], k1 = ei[NE + e];
  if (k0 != k1) {
    int p = atomicAdd(&cursor[k1], 1);
    elist[starts[k1] + p] = e;
  }
}

// fallback finalize (atomic path only)
__global__ void finalize_kernel(const float* __restrict__ xx,
                                const int* __restrict__ degi,
                                const float* __restrict__ dp,
                                const float* __restrict__ x_res,
                                float* __restrict__ out) {
  int idx = blockIdx.x * blockDim.x + threadIdx.x;
  if (idx >= NN * CC) return;
  int n = idx >> 8, c = idx & 255;
  float d = (float)(degi[n] > 1 ? degi[n] : 1);
  out[idx] = powf(d, dp[c]) * xx[idx] + x_res[idx];
}

// ---------------- fused all-register edge kernel ----------------
// Block = 4 waves = 2 tile-pairs x 2 c-halves. Wave: 2 e-tiles (32 edges),
// half the post output channels. One barrier (bias exchange).
// MODE 0: plain bf16 stores of per-edge messages to MSG (no atomics).
// MODE 1: fallback — masked fp32 atomic scatter into xx (round-6 proven).
template <int MODE>
__global__ __launch_bounds__(256, 4) void edge_fused(
    const unsigned short* __restrict__ x0g, const unsigned short* __restrict__ x1g,
    const float* __restrict__ z_rw, const int* __restrict__ ei,
    const unsigned short* __restrict__ Fpre,
    const unsigned short* __restrict__ Fg_p, const unsigned short* __restrict__ Fv_p,
    const unsigned short* __restrict__ Fp_p,
    const unsigned short* __restrict__ Fg_f, const unsigned short* __restrict__ Fv_f,
    const unsigned short* __restrict__ Fp_f,
    float* __restrict__ xx, unsigned short* __restrict__ MSG) {
  __shared__ s16x4 BLDS[4][16][64];     // 32KB bias frag exchange
  __shared__ int K0s[64], K1s[64];      // used by MODE 1 only

  const int tid = threadIdx.x;
  const int lane = tid & 63;
  const int w = tid >> 6;
  const int el = lane & 15, q = lane >> 4;
  const int chalf = w & 1;              // post output-channel half
  const int tp = w >> 1;                // tile-pair 0/1
  const int ebase = blockIdx.x * 64 + tp * 32;
  const f32x4 zero4 = {0.f, 0.f, 0.f, 0.f};

  int k0[2], k1[2];
  #pragma unroll
  for (int t = 0; t < 2; t++) {
    k0[t] = ei[ebase + t * 16 + el];
    k1[t] = ei[NE + ebase + t * 16 + el];
  }
  if (MODE == 1 && chalf == 0 && q == 0) {
    #pragma unroll
    for (int t = 0; t < 2; t++) {
      K0s[tp * 32 + t * 16 + el] = k0[t];
      K1s[tp * 32 + t * 16 + el] = k1[t];
    }
  }

  // z B-frags: bz0 = z_rw[k0] (k 0..15), bz1 = z_rw[k1] (k 16..31)
  s16x4 bz0[2], bz1[2];
  #pragma unroll
  for (int t = 0; t < 2; t++) {
    float4 a = *(const float4*)(z_rw + (size_t)k0[t] * 16 + q * 4);
    float4 b = *(const float4*)(z_rw + (size_t)k1[t] * 16 + q * 4);
    bz0[t][0] = (short)f2bf(a.x); bz0[t][1] = (short)f2bf(a.y);
    bz0[t][2] = (short)f2bf(a.z); bz0[t][3] = (short)f2bf(a.w);
    bz1[t][0] = (short)f2bf(b.x); bz1[t][1] = (short)f2bf(b.y);
    bz1[t][2] = (short)f2bf(b.z); bz1[t][3] = (short)f2bf(b.w);
  }

  f32x4 acc[2][8];
  #pragma unroll
  for (int t = 0; t < 2; t++)
    #pragma unroll
    for (int c8 = 0; c8 < 8; c8++) acc[t][c8] = zero4;

  // ================= perw block (per-h fused) =================
  #pragma unroll
  for (int h = 0; h < 8; h++) {
    f32x4 pr[2][2];
    #pragma unroll
    for (int mt2 = 0; mt2 < 2; mt2++) {
      int mt = 2 * h + mt2;
      s16x4 fa0 = FR(Fpre, mt, lane);
      s16x4 fa1 = FR(Fpre, 16 + mt, lane);
      #pragma unroll
      for (int t = 0; t < 2; t++) {
        f32x4 d = MFMA16(fa0, bz0[t], zero4);
        pr[t][mt2] = MFMA16(fa1, bz1[t], d);
      }
    }
    s16x4 t16[2][2];
    #pragma unroll
    for (int t = 0; t < 2; t++) {
      float s1 = 0.f, s2 = 0.f;
      #pragma unroll
      for (int mt2 = 0; mt2 < 2; mt2++)
        #pragma unroll
        for (int j = 0; j < 4; j++) {
          float v = pr[t][mt2][j];
          s1 += v; s2 += v * v;
        }
      s1 += __shfl_xor(s1, 16); s1 += __shfl_xor(s1, 32);
      s2 += __shfl_xor(s2, 16); s2 += __shfl_xor(s2, 32);
      float mu = s1 * (1.f / 32.f);
      float var = fmaxf(s2 * (1.f / 32.f) - mu * mu, 0.f);
      float ri = rsqrtf(var + 1e-5f);
      #pragma unroll
      for (int mt2 = 0; mt2 < 2; mt2++) {
        f32x4 n;
        #pragma unroll
        for (int j = 0; j < 4; j++) n[j] = (pr[t][mt2][j] - mu) * ri;
        t16[t][mt2] = pack4(n);
      }
    }
    #pragma unroll
    for (int ot = 0; ot < 4; ot++) {
      int kpc = h * 4 + ot;
      s16x4 fg0 = FR(Fg_p, kpc, lane), fg1 = FR(Fg_p, 32 + kpc, lane);
      s16x4 fv0 = FR(Fv_p, kpc, lane), fv1 = FR(Fv_p, 32 + kpc, lane);
      s16x4 u[2];
      #pragma unroll
      for (int t = 0; t < 2; t++) {
        f32x4 g = MFMA16(fg0, t16[t][0], zero4);
        g = MFMA16(fg1, t16[t][1], g);
        f32x4 v = MFMA16(fv0, t16[t][0], zero4);
        v = MFMA16(fv1, t16[t][1], v);
        f32x4 uf;
        #pragma unroll
        for (int j = 0; j < 4; j++) uf[j] = fmaxf(g[j], 0.f) * v[j];
        u[t] = pack4(uf);
      }
      #pragma unroll
      for (int c8 = 0; c8 < 8; c8++) {
        s16x4 fp = FR(Fp_p, kpc * 16 + chalf * 8 + c8, lane);
        #pragma unroll
        for (int t = 0; t < 2; t++)
          acc[t][c8] = MFMA16(fp, u[t], acc[t][c8]);   // A=W: rows=out-ch
      }
    }
  }

  // ---- bias exchange (only barrier) ----
  #pragma unroll
  for (int t = 0; t < 2; t++)
    #pragma unroll
    for (int c8 = 0; c8 < 8; c8++)
      BLDS[tp * 2 + t][chalf * 8 + c8][lane] = pack4(acc[t][c8]);
  __syncthreads();

  // ================= ffn block (per-h fused) =================
  #pragma unroll
  for (int t = 0; t < 2; t++)
    #pragma unroll
    for (int c8 = 0; c8 < 8; c8++) acc[t][c8] = zero4;

  #pragma unroll
  for (int h = 0; h < 8; h++) {
    f32x4 nm[2][2];
    s16x4 tv16[2][2], tg16[2][2];
    #pragma unroll
    for (int t = 0; t < 2; t++) {
      f32x4 m[2];
      #pragma unroll
      for (int mt2 = 0; mt2 < 2; mt2++) {
        int mt = 2 * h + mt2;
        s16x4 a = ntload4(x0g + (size_t)k0[t] * 256 + mt * 16 + q * 4);
        s16x4 b = ntload4(x1g + (size_t)k1[t] * 256 + mt * 16 + q * 4);
        #pragma unroll
        for (int j = 0; j < 4; j++)
          m[mt2][j] = bf2f((unsigned short)a[j]) + bf2f((unsigned short)b[j]);
      }
      float s1 = 0.f, s2 = 0.f;
      #pragma unroll
      for (int mt2 = 0; mt2 < 2; mt2++)
        #pragma unroll
        for (int j = 0; j < 4; j++) { s1 += m[mt2][j]; s2 += m[mt2][j] * m[mt2][j]; }
      s1 += __shfl_xor(s1, 16); s1 += __shfl_xor(s1, 32);
      s2 += __shfl_xor(s2, 16); s2 += __shfl_xor(s2, 32);
      float mu = s1 * (1.f / 32.f);
      float var = fmaxf(s2 * (1.f / 32.f) - mu * mu, 0.f);
      float ri = rsqrtf(var + 1e-5f);
      s16x4 b0 = BLDS[tp * 2 + t][2 * h][lane];
      s16x4 b1 = BLDS[tp * 2 + t][2 * h + 1][lane];
      f32x4 bb0 = up4(b0), bb1 = up4(b1);
      #pragma unroll
      for (int mt2 = 0; mt2 < 2; mt2++) {
        #pragma unroll
        for (int j = 0; j < 4; j++) nm[t][mt2][j] = (m[mt2][j] - mu) * ri;
        tv16[t][mt2] = pack4(nm[t][mt2]);
      }
      f32x4 g0, g1;
      #pragma unroll
      for (int j = 0; j < 4; j++) {
        g0[j] = nm[t][0][j] + bb0[j];
        g1[j] = nm[t][1][j] + bb1[j];
      }
      tg16[t][0] = pack4(g0);
      tg16[t][1] = pack4(g1);
    }
    #pragma unroll
    for (int ot = 0; ot < 4; ot++) {
      int kpc = h * 4 + ot;
      s16x4 fg0 = FR(Fg_f, kpc, lane), fg1 = FR(Fg_f, 32 + kpc, lane);
      s16x4 fv0 = FR(Fv_f, kpc, lane), fv1 = FR(Fv_f, 32 + kpc, lane);
      s16x4 u[2];
      #pragma unroll
      for (int t = 0; t < 2; t++) {
        f32x4 g = MFMA16(fg0, tg16[t][0], zero4);
        g = MFMA16(fg1, tg16[t][1], g);
        f32x4 v = MFMA16(fv0, tv16[t][0], zero4);
        v = MFMA16(fv1, tv16[t][1], v);
        f32x4 uf;
        #pragma unroll
        for (int j = 0; j < 4; j++) uf[j] = fmaxf(g[j], 0.f) * v[j];
        u[t] = pack4(uf);
      }
      #pragma unroll
      for (int c8 = 0; c8 < 8; c8++) {
        s16x4 fb = FR(Fp_f, kpc * 16 + chalf * 8 + c8, lane);
        #pragma unroll
        for (int t = 0; t < 2; t++) {
          if (MODE == 0)
            acc[t][c8] = MFMA16(fb, u[t], acc[t][c8]);   // rows=out-ch
          else
            acc[t][c8] = MFMA16(u[t], fb, acc[t][c8]);   // cols=out-ch
        }
      }
    }
  }

  if (MODE == 0) {
    // lane (el,q) holds channels (chalf*8+c8)*16 + q*4 + r of edge el
    #pragma unroll
    for (int t = 0; t < 2; t++) {
      unsigned short* mrow = MSG + (size_t)(ebase + t * 16 + el) * 256 +
                             chalf * 128 + q * 4;
      #pragma unroll
      for (int c8 = 0; c8 < 8; c8++)
        __builtin_nontemporal_store(pack4(acc[t][c8]), (s16x4*)(mrow + c8 * 16));
    }
  } else {
    #pragma unroll
    for (int t = 0; t < 2; t++) {
      #pragma unroll
      for (int r = 0; r < 4; r++) {
        int eL = tp * 32 + t * 16 + q * 4 + r;
        int kk0 = K0s[eL], kk1 = K1s[eL];
        if (kk0 != kk1) {
          float* dst = xx + (size_t)kk1 * 256 + chalf * 128 + el;
          #pragma unroll
          for (int c8 = 0; c8 < 8; c8++)
            atomicAdd(dst + c8 * 16, acc[t][c8][r]);
        }
      }
    }
  }
}

// per-node aggregation + degree-power + residual (fuses finalize)
__global__ __launch_bounds__(256) void aggregate_kernel(
    const unsigned short* __restrict__ MSG, const int* __restrict__ elist,
    const int* __restrict__ starts, const int* __restrict__ degi,
    const float* __restrict__ dp, const float* __restrict__ x_res,
    float* __restrict__ out) {
  int wid = threadIdx.x >> 6, lane = threadIdx.x & 63;
  int n = blockIdx.x * 4 + wid;
  if (n >= NN) return;
  int i = starts[n], en = starts[n + 1];
  float a0 = 0.f, a1 = 0.f, a2 = 0.f, a3 = 0.f;
  for (; i + 2 <= en; i += 2) {
    int e0 = elist[i], e1 = elist[i + 1];
    s16x4 v0 = __builtin_nontemporal_load((const s16x4*)(MSG + (size_t)e0 * 256 + lane * 4));
    s16x4 v1 = __builtin_nontemporal_load((const s16x4*)(MSG + (size_t)e1 * 256 + lane * 4));
    a0 += bf2f((unsigned short)v0[0]) + bf2f((unsigned short)v1[0]);
    a1 += bf2f((unsigned short)v0[1]) + bf2f((unsigned short)v1[1]);
    a2 += bf2f((unsigned short)v0[2]) + bf2f((unsigned short)v1[2]);
    a3 += bf2f((unsigned short)v0[3]) + bf2f((unsigned short)v1[3]);
  }
  if (i < en) {
    int e0 = elist[i];
    s16x4 v0 = __builtin_nontemporal_load((const s16x4*)(MSG + (size_t)e0 * 256 + lane * 4));
    a0 += bf2f((unsigned short)v0[0]);
    a1 += bf2f((unsigned short)v0[1]);
    a2 += bf2f((unsigned short)v0[2]);
    a3 += bf2f((unsigned short)v0[3]);
  }
  float d = (float)(degi[n] > 1 ? degi[n] : 1);
  float l2 = __log2f(d);
  float4 dpv = *(const float4*)(dp + lane * 4);
  float4 xr = *(const float4*)(x_res + (size_t)n * CC + lane * 4);
  float4 o;
  o.x = exp2f(l2 * dpv.x) * a0 + xr.x;
  o.y = exp2f(l2 * dpv.y) * a1 + xr.y;
  o.z = exp2f(l2 * dpv.z) * a2 + xr.z;
  o.w = exp2f(l2 * dpv.w) * a3 + xr.w;
  *(float4*)(out + (size_t)n * CC + lane * 4) = o;
}

extern "C" void kernel_launch(void* const* d_in, const int* in_sizes, int n_in,
                              void* d_out, int out_size, void* d_ws, size_t ws_size,
                              hipStream_t stream) {
  (void)in_sizes; (void)n_in; (void)out_size;
  const float* x        = (const float*)d_in[0];
  const float* x_res    = (const float*)d_in[1];
  const float* z_rw     = (const float*)d_in[2];
  const int*   ei       = (const int*)d_in[3];
  const float* w_src    = (const float*)d_in[4];
  const float* w_tgt    = (const float*)d_in[5];
  const float* w_pre    = (const float*)d_in[6];
  const float* w_gate_p = (const float*)d_in[7];
  const float* w_val_p  = (const float*)d_in[8];
  const float* w_post_p = (const float*)d_in[9];
  const float* w_gate_f = (const float*)d_in[10];
  const float* w_val_f  = (const float*)d_in[11];
  const float* w_post_f = (const float*)d_in[12];
  const float* dparam   = (const float*)d_in[13];
  float* out = (float*)d_out;

  // ---- workspace layout (256B aligned) ----
  char* W = (char*)d_ws;
  size_t off = 0;
  auto alloc = [&](size_t bytes) {
    size_t o = off;
    off = (off + bytes + 255) & ~(size_t)255;
    return o;
  };
  unsigned short* x0     = (unsigned short*)(W + alloc((size_t)NN * CC * 2));
  unsigned short* x1     = (unsigned short*)(W + alloc((size_t)NN * CC * 2));
  unsigned short* Fpre   = (unsigned short*)(W + alloc(8192 * 2));
  unsigned short* Fg_p   = (unsigned short*)(W + alloc(16384 * 2));
  unsigned short* Fv_p   = (unsigned short*)(W + alloc(16384 * 2));
  unsigned short* Fp_p   = (unsigned short*)(W + alloc(131072 * 2));
  unsigned short* Fg_f   = (unsigned short*)(W + alloc(16384 * 2));
  unsigned short* Fv_f   = (unsigned short*)(W + alloc(16384 * 2));
  unsigned short* Fp_f   = (unsigned short*)(W + alloc(131072 * 2));
  int* degi              = (int*)(W + alloc(2 * (size_t)NN * 4));  // degi+cursor
  int* cursor            = degi + NN;
  int* starts            = (int*)(W + alloc(((size_t)NN + 1) * 4));
  int* elist             = (int*)(W + alloc((size_t)NE * 4));
  size_t tail = off;
  unsigned short* MSG = (unsigned short*)(W + tail);   // NE*CC*2 = 164MB
  float* xx           = (float*)(W + tail);            // NN*CC*4 = 20.5MB (fallback)
  bool use_msg = (tail + (size_t)NE * CC * 2) <= ws_size;

  hipMemsetAsync(degi, 0, 2 * (size_t)NN * 4, stream);

  repack_kernel<<<8, 256, 0, stream>>>(w_pre, Fpre, 16, 2);
  repack_kernel<<<16, 256, 0, stream>>>(w_gate_p, Fg_p, 32, 2);
  repack_kernel<<<16, 256, 0, stream>>>(w_val_p, Fv_p, 32, 2);
  repack_kernel<<<128, 256, 0, stream>>>(w_post_p, Fp_p, 16, 32);
  repack_kernel<<<16, 256, 0, stream>>>(w_gate_f, Fg_f, 32, 2);
  repack_kernel<<<16, 256, 0, stream>>>(w_val_f, Fv_f, 32, 2);
  repack_kernel<<<128, 256, 0, stream>>>(w_post_f, Fp_f, 16, 32);

  proj_kernel<<<dim3(NN / 32, 2), 256, 0, stream>>>(x, w_src, w_tgt, x0, x1);
  deg_int_kernel<<<(NE + 255) / 256, 256, 0, stream>>>(ei, degi);

  if (use_msg) {
    prefix_kernel<<<1, 64, 0, stream>>>(degi, starts);
    fill_kernel<<<(NE + 255) / 256, 256, 0, stream>>>(ei, starts, cursor, elist);
    edge_fused<0><<<NE / 64, 256, 0, stream>>>(x0, x1, z_rw, ei,
                                               Fpre, Fg_p, Fv_p, Fp_p,
                                               Fg_f, Fv_f, Fp_f, nullptr, MSG);
    aggregate_kernel<<<(NN + 3) / 4, 256, 0, stream>>>(MSG, elist, starts, degi,
                                                       dparam, x_res, out);
  } else {
    hipMemsetAsync(xx, 0, (size_t)NN * CC * 4, stream);
    edge_fused<1><<<NE / 64, 256, 0, stream>>>(x0, x1, z_rw, ei,
                                               Fpre, Fg_p, Fv_p, Fp_p,
                                               Fg_f, Fv_f, Fp_f, xx, nullptr);
    finalize_kernel<<<(NN * CC + 255) / 256, 256, 0, stream>>>(xx, degi, dparam,
                                                               x_res, out);
  }
}

// Round 8
// 3026.908 us; speedup vs baseline: 1.8356x; 1.0335x over previous
//
#include <hip/hip_runtime.h>
#include <hip/hip_bf16.h>

// Problem constants (fixed by the reference)
#define NN   20000      // nodes
#define NE   320000     // edges
#define CC   256        // width
#define CA   512        // width_act

typedef __attribute__((ext_vector_type(4))) short s16x4;   // 4 bf16 (2 VGPRs)
typedef __attribute__((ext_vector_type(4))) float f32x4;   // MFMA accumulator

__device__ __forceinline__ unsigned short f2bf(float f) {
  unsigned int u = __float_as_uint(f);
  u += 0x7fff + ((u >> 16) & 1);          // RNE
  return (unsigned short)(u >> 16);
}
__device__ __forceinline__ float bf2f(unsigned short h) {
  return __uint_as_float(((unsigned int)h) << 16);
}

// K=16 bf16 MFMA: operand frag (A or B): elem j = M[row=lane&15][k=(lane>>4)*4+j].
// D: col = lane&15 (N), row = (lane>>4)*4 + reg (M).  (validated rounds 4/6/7)
#if defined(__has_builtin)
#if __has_builtin(__builtin_amdgcn_mfma_f32_16x16x16bf16_1k)
#define HAVE_MFMA1K 1
#endif
#endif
__device__ __forceinline__ f32x4 MFMA16(s16x4 a, s16x4 b, f32x4 c) {
#ifdef HAVE_MFMA1K
  return __builtin_amdgcn_mfma_f32_16x16x16bf16_1k(a, b, c, 0, 0, 0);
#else
  f32x4 d;
  asm volatile("v_mfma_f32_16x16x16_bf16 %0, %1, %2, %3"
               : "=&v"(d) : "v"(a), "v"(b), "v"(c));
  return d;
#endif
}

__device__ __forceinline__ s16x4 FR(const unsigned short* base, int f, int lane) {
  return *(const s16x4*)(base + (size_t)f * 256 + lane * 4);
}
__device__ __forceinline__ s16x4 pack4(f32x4 v) {
  s16x4 o;
  #pragma unroll
  for (int j = 0; j < 4; j++) o[j] = (short)f2bf(v[j]);
  return o;
}
__device__ __forceinline__ f32x4 up4(s16x4 v) {
  f32x4 o;
  #pragma unroll
  for (int j = 0; j < 4; j++) o[j] = bf2f((unsigned short)v[j]);
  return o;
}

// ---- repack weights [O][K] f32 -> frag-major bf16: frag f = kt*(O/16)+ot,
// frag[lane=(el,q)][j] = W[ot*16+el][kt*16+q*4+j], 512B per frag ----
__global__ void repack_kernel(const float* __restrict__ src,
                              unsigned short* __restrict__ dst,
                              int OT, int KT) {
  int g = blockIdx.x * 256 + threadIdx.x;
  if (g >= OT * KT * 64) return;
  int lane = g & 63, f = g >> 6;
  int kt = f / OT, ot = f - kt * OT;
  int el = lane & 15, q = lane >> 4;
  const float* s = src + (size_t)(ot * 16 + el) * (KT * 16) + kt * 16 + q * 4;
  unsigned short* d = dst + (size_t)f * 256 + lane * 4;
  d[0] = f2bf(s[0]); d[1] = f2bf(s[1]); d[2] = f2bf(s[2]); d[3] = f2bf(s[3]);
}

__global__ __launch_bounds__(256) void proj_kernel(
    const float* __restrict__ x, const float* __restrict__ w_src,
    const float* __restrict__ w_tgt, unsigned short* __restrict__ x0,
    unsigned short* __restrict__ x1) {
  __shared__ float xs[32 * 256];
  const int tid = threadIdx.x;
  const int row0 = blockIdx.x * 32;
  const float* w = blockIdx.y ? w_tgt : w_src;
  unsigned short* out = blockIdx.y ? x1 : x0;

  const float4* src = (const float4*)(x + (size_t)row0 * CC);
  float4* dstv = (float4*)xs;
  for (int i = tid; i < 2048; i += 256) dstv[i] = src[i];
  __syncthreads();

  const int c = tid;
  float acc[32];
  #pragma unroll
  for (int r = 0; r < 32; r++) acc[r] = 0.f;
  for (int k = 0; k < 256; k += 4) {
    float4 wv = *(const float4*)(w + (size_t)c * CC + k);
    #pragma unroll
    for (int r = 0; r < 32; r++) {
      float4 xv = *(const float4*)(&xs[r * 256 + k]);
      acc[r] += xv.x * wv.x + xv.y * wv.y + xv.z * wv.z + xv.w * wv.w;
    }
  }
  #pragma unroll
  for (int r = 0; r < 32; r++) out[(size_t)(row0 + r) * CC + c] = f2bf(acc[r]);
}

__global__ void deg_int_kernel(const int* __restrict__ ei, int* __restrict__ degi) {
  int e = blockIdx.x * blockDim.x + threadIdx.x;
  if (e >= NE) return;
  int k0 = ei[e], k1 = ei[NE + e];
  if (k0 != k1) atomicAdd(&degi[k1], 1);
}

// exclusive prefix sum over degi[NN] -> starts[NN+1]; 1 block of 64 lanes
__global__ __launch_bounds__(64) void prefix_kernel(const int* __restrict__ degi,
                                                    int* __restrict__ starts) {
  int lane = threadIdx.x;
  int runoff = 0;
  for (int base = 0; base < NN; base += 64) {
    int v = (base + lane < NN) ? degi[base + lane] : 0;
    int s = v;
    #pragma unroll
    for (int o = 1; o < 64; o <<= 1) {
      int x = __shfl_up(s, o);
      if (lane >= o) s += x;
    }
    if (base + lane < NN) starts[base + lane] = runoff + s - v;
    runoff += __shfl(s, 63);
  }
  if (lane == 0) starts[NN] = runoff;
}

__global__ void fill_kernel(const int* __restrict__ ei, const int* __restrict__ starts,
                            int* __restrict__ cursor, int* __restrict__ elist) {
  int e = blockIdx.x * blockDim.x + threadIdx.x;
  if (e >= NE) return;
  int k0 = ei[e], k1 = ei[NE + e];
  if (k0 != k1) {
    int p = atomicAdd(&cursor[k1], 1);
    elist[starts[k1] + p] = e;
  }
}

// fallback finalize (atomic path only)
__global__ void finalize_kernel(const float* __restrict__ xx,
                                const int* __restrict__ degi,
                                const float* __restrict__ dp,
                                const float* __restrict__ x_res,
                                float* __restrict__ out) {
  int idx = blockIdx.x * blockDim.x + threadIdx.x;
  if (idx >= NN * CC) return;
  int n = idx >> 8, c = idx & 255;
  float d = (float)(degi[n] > 1 ? degi[n] : 1);
  out[idx] = powf(d, dp[c]) * xx[idx] + x_res[idx];
}

// ---------------- fused all-register edge kernel ----------------
// Block = 4 waves = 2 tile-pairs x 2 c-halves. Wave: 2 e-tiles (32 edges),
// half the post output channels. One barrier (bias exchange).
// MODE 0: edges processed in CSR (k1-grouped) slot order via elist ->
//         destination gathers are L2-hits; messages stored densely (plain
//         cached stores, L2 merges partial lines).
// MODE 1: fallback — original order, masked fp32 atomic scatter into xx.
template <int MODE>
__global__ __launch_bounds__(256, 4) void edge_fused(
    const unsigned short* __restrict__ x0g, const unsigned short* __restrict__ x1g,
    const float* __restrict__ z_rw, const int* __restrict__ ei,
    const int* __restrict__ elist, const int* __restrict__ starts,
    const unsigned short* __restrict__ Fpre,
    const unsigned short* __restrict__ Fg_p, const unsigned short* __restrict__ Fv_p,
    const unsigned short* __restrict__ Fp_p,
    const unsigned short* __restrict__ Fg_f, const unsigned short* __restrict__ Fv_f,
    const unsigned short* __restrict__ Fp_f,
    float* __restrict__ xx, unsigned short* __restrict__ MSG) {
  __shared__ s16x4 BLDS[4][16][64];     // 32KB bias frag exchange
  __shared__ int K0s[64], K1s[64];      // used by MODE 1 only

  const int tid = threadIdx.x;
  const int lane = tid & 63;
  const int w = tid >> 6;
  const int el = lane & 15, q = lane >> 4;
  const int chalf = w & 1;              // post output-channel half
  const int tp = w >> 1;                // tile-pair 0/1
  const int ebase = blockIdx.x * 64 + tp * 32;
  const f32x4 zero4 = {0.f, 0.f, 0.f, 0.f};

  int k0[2], k1[2];
  int slot[2];
  bool ok[2];
  if (MODE == 0) {
    const int nv = starts[NN];          // number of valid (non-self) edges
    #pragma unroll
    for (int t = 0; t < 2; t++) {
      slot[t] = ebase + t * 16 + el;
      ok[t] = slot[t] < nv;
      int e = ok[t] ? elist[slot[t]] : (nv > 0 ? elist[0] : 0);
      k0[t] = ei[e];
      k1[t] = ei[NE + e];
    }
  } else {
    #pragma unroll
    for (int t = 0; t < 2; t++) {
      slot[t] = 0; ok[t] = true;
      k0[t] = ei[ebase + t * 16 + el];
      k1[t] = ei[NE + ebase + t * 16 + el];
    }
    if (chalf == 0 && q == 0) {
      #pragma unroll
      for (int t = 0; t < 2; t++) {
        K0s[tp * 32 + t * 16 + el] = k0[t];
        K1s[tp * 32 + t * 16 + el] = k1[t];
      }
    }
  }

  // z B-frags: bz0 = z_rw[k0] (k 0..15), bz1 = z_rw[k1] (k 16..31)
  s16x4 bz0[2], bz1[2];
  #pragma unroll
  for (int t = 0; t < 2; t++) {
    float4 a = *(const float4*)(z_rw + (size_t)k0[t] * 16 + q * 4);
    float4 b = *(const float4*)(z_rw + (size_t)k1[t] * 16 + q * 4);
    bz0[t][0] = (short)f2bf(a.x); bz0[t][1] = (short)f2bf(a.y);
    bz0[t][2] = (short)f2bf(a.z); bz0[t][3] = (short)f2bf(a.w);
    bz1[t][0] = (short)f2bf(b.x); bz1[t][1] = (short)f2bf(b.y);
    bz1[t][2] = (short)f2bf(b.z); bz1[t][3] = (short)f2bf(b.w);
  }

  f32x4 acc[2][8];
  #pragma unroll
  for (int t = 0; t < 2; t++)
    #pragma unroll
    for (int c8 = 0; c8 < 8; c8++) acc[t][c8] = zero4;

  // ================= perw block (per-h fused) =================
  #pragma unroll
  for (int h = 0; h < 8; h++) {
    f32x4 pr[2][2];
    #pragma unroll
    for (int mt2 = 0; mt2 < 2; mt2++) {
      int mt = 2 * h + mt2;
      s16x4 fa0 = FR(Fpre, mt, lane);
      s16x4 fa1 = FR(Fpre, 16 + mt, lane);
      #pragma unroll
      for (int t = 0; t < 2; t++) {
        f32x4 d = MFMA16(fa0, bz0[t], zero4);
        pr[t][mt2] = MFMA16(fa1, bz1[t], d);
      }
    }
    s16x4 t16[2][2];
    #pragma unroll
    for (int t = 0; t < 2; t++) {
      float s1 = 0.f, s2 = 0.f;
      #pragma unroll
      for (int mt2 = 0; mt2 < 2; mt2++)
        #pragma unroll
        for (int j = 0; j < 4; j++) {
          float v = pr[t][mt2][j];
          s1 += v; s2 += v * v;
        }
      s1 += __shfl_xor(s1, 16); s1 += __shfl_xor(s1, 32);
      s2 += __shfl_xor(s2, 16); s2 += __shfl_xor(s2, 32);
      float mu = s1 * (1.f / 32.f);
      float var = fmaxf(s2 * (1.f / 32.f) - mu * mu, 0.f);
      float ri = rsqrtf(var + 1e-5f);
      #pragma unroll
      for (int mt2 = 0; mt2 < 2; mt2++) {
        f32x4 n;
        #pragma unroll
        for (int j = 0; j < 4; j++) n[j] = (pr[t][mt2][j] - mu) * ri;
        t16[t][mt2] = pack4(n);
      }
    }
    #pragma unroll
    for (int ot = 0; ot < 4; ot++) {
      int kpc = h * 4 + ot;
      s16x4 fg0 = FR(Fg_p, kpc, lane), fg1 = FR(Fg_p, 32 + kpc, lane);
      s16x4 fv0 = FR(Fv_p, kpc, lane), fv1 = FR(Fv_p, 32 + kpc, lane);
      s16x4 u[2];
      #pragma unroll
      for (int t = 0; t < 2; t++) {
        f32x4 g = MFMA16(fg0, t16[t][0], zero4);
        g = MFMA16(fg1, t16[t][1], g);
        f32x4 v = MFMA16(fv0, t16[t][0], zero4);
        v = MFMA16(fv1, t16[t][1], v);
        f32x4 uf;
        #pragma unroll
        for (int j = 0; j < 4; j++) uf[j] = fmaxf(g[j], 0.f) * v[j];
        u[t] = pack4(uf);
      }
      #pragma unroll
      for (int c8 = 0; c8 < 8; c8++) {
        s16x4 fp = FR(Fp_p, kpc * 16 + chalf * 8 + c8, lane);
        #pragma unroll
        for (int t = 0; t < 2; t++)
          acc[t][c8] = MFMA16(fp, u[t], acc[t][c8]);   // A=W: rows=out-ch
      }
    }
  }

  // ---- bias exchange (only barrier) ----
  #pragma unroll
  for (int t = 0; t < 2; t++)
    #pragma unroll
    for (int c8 = 0; c8 < 8; c8++)
      BLDS[tp * 2 + t][chalf * 8 + c8][lane] = pack4(acc[t][c8]);
  __syncthreads();

  // ================= ffn block (per-h fused) =================
  #pragma unroll
  for (int t = 0; t < 2; t++)
    #pragma unroll
    for (int c8 = 0; c8 < 8; c8++) acc[t][c8] = zero4;

  #pragma unroll
  for (int h = 0; h < 8; h++) {
    f32x4 nm[2][2];
    s16x4 tv16[2][2], tg16[2][2];
    #pragma unroll
    for (int t = 0; t < 2; t++) {
      f32x4 m[2];
      #pragma unroll
      for (int mt2 = 0; mt2 < 2; mt2++) {
        int mt = 2 * h + mt2;
        s16x4 a = *(const s16x4*)(x0g + (size_t)k0[t] * 256 + mt * 16 + q * 4);
        s16x4 b = *(const s16x4*)(x1g + (size_t)k1[t] * 256 + mt * 16 + q * 4);
        #pragma unroll
        for (int j = 0; j < 4; j++)
          m[mt2][j] = bf2f((unsigned short)a[j]) + bf2f((unsigned short)b[j]);
      }
      float s1 = 0.f, s2 = 0.f;
      #pragma unroll
      for (int mt2 = 0; mt2 < 2; mt2++)
        #pragma unroll
        for (int j = 0; j < 4; j++) { s1 += m[mt2][j]; s2 += m[mt2][j] * m[mt2][j]; }
      s1 += __shfl_xor(s1, 16); s1 += __shfl_xor(s1, 32);
      s2 += __shfl_xor(s2, 16); s2 += __shfl_xor(s2, 32);
      float mu = s1 * (1.f / 32.f);
      float var = fmaxf(s2 * (1.f / 32.f) - mu * mu, 0.f);
      float ri = rsqrtf(var + 1e-5f);
      s16x4 b0 = BLDS[tp * 2 + t][2 * h][lane];
      s16x4 b1 = BLDS[tp * 2 + t][2 * h + 1][lane];
      f32x4 bb0 = up4(b0), bb1 = up4(b1);
      #pragma unroll
      for (int mt2 = 0; mt2 < 2; mt2++) {
        #pragma unroll
        for (int j = 0; j < 4; j++) nm[t][mt2][j] = (m[mt2][j] - mu) * ri;
        tv16[t][mt2] = pack4(nm[t][mt2]);
      }
      f32x4 g0, g1;
      #pragma unroll
      for (int j = 0; j < 4; j++) {
        g0[j] = nm[t][0][j] + bb0[j];
        g1[j] = nm[t][1][j] + bb1[j];
      }
      tg16[t][0] = pack4(g0);
      tg16[t][1] = pack4(g1);
    }
    #pragma unroll
    for (int ot = 0; ot < 4; ot++) {
      int kpc = h * 4 + ot;
      s16x4 fg0 = FR(Fg_f, kpc, lane), fg1 = FR(Fg_f, 32 + kpc, lane);
      s16x4 fv0 = FR(Fv_f, kpc, lane), fv1 = FR(Fv_f, 32 + kpc, lane);
      s16x4 u[2];
      #pragma unroll
      for (int t = 0; t < 2; t++) {
        f32x4 g = MFMA16(fg0, tg16[t][0], zero4);
        g = MFMA16(fg1, tg16[t][1], g);
        f32x4 v = MFMA16(fv0, tv16[t][0], zero4);
        v = MFMA16(fv1, tv16[t][1], v);
        f32x4 uf;
        #pragma unroll
        for (int j = 0; j < 4; j++) uf[j] = fmaxf(g[j], 0.f) * v[j];
        u[t] = pack4(uf);
      }
      #pragma unroll
      for (int c8 = 0; c8 < 8; c8++) {
        s16x4 fb = FR(Fp_f, kpc * 16 + chalf * 8 + c8, lane);
        #pragma unroll
        for (int t = 0; t < 2; t++) {
          if (MODE == 0)
            acc[t][c8] = MFMA16(fb, u[t], acc[t][c8]);   // rows=out-ch
          else
            acc[t][c8] = MFMA16(u[t], fb, acc[t][c8]);   // cols=out-ch
        }
      }
    }
  }

  if (MODE == 0) {
    // lane (el,q) holds channels chalf*128 + c8*16 + q*4 + r of slot[t]
    #pragma unroll
    for (int t = 0; t < 2; t++) {
      if (!ok[t]) continue;
      unsigned short* mrow = MSG + (size_t)slot[t] * 256 + chalf * 128 + q * 4;
      #pragma unroll
      for (int c8 = 0; c8 < 8; c8++)
        *(s16x4*)(mrow + c8 * 16) = pack4(acc[t][c8]);
    }
  } else {
    #pragma unroll
    for (int t = 0; t < 2; t++) {
      #pragma unroll
      for (int r = 0; r < 4; r++) {
        int eL = tp * 32 + t * 16 + q * 4 + r;
        int kk0 = K0s[eL], kk1 = K1s[eL];
        if (kk0 != kk1) {
          float* dst = xx + (size_t)kk1 * 256 + chalf * 128 + el;
          #pragma unroll
          for (int c8 = 0; c8 < 8; c8++)
            atomicAdd(dst + c8 * 16, acc[t][c8][r]);
        }
      }
    }
  }
}

// per-node aggregation over CONTIGUOUS slots + degree-power + residual
__global__ __launch_bounds__(256) void aggregate_kernel(
    const unsigned short* __restrict__ MSG, const int* __restrict__ starts,
    const float* __restrict__ dp, const float* __restrict__ x_res,
    float* __restrict__ out) {
  int wid = threadIdx.x >> 6, lane = threadIdx.x & 63;
  int n = blockIdx.x * 4 + wid;
  if (n >= NN) return;
  int i0 = starts[n], en = starts[n + 1];
  float a0 = 0.f, a1 = 0.f, a2 = 0.f, a3 = 0.f;
  int i = i0;
  for (; i + 2 <= en; i += 2) {
    s16x4 v0 = *(const s16x4*)(MSG + (size_t)i * 256 + lane * 4);
    s16x4 v1 = *(const s16x4*)(MSG + (size_t)(i + 1) * 256 + lane * 4);
    a0 += bf2f((unsigned short)v0[0]) + bf2f((unsigned short)v1[0]);
    a1 += bf2f((unsigned short)v0[1]) + bf2f((unsigned short)v1[1]);
    a2 += bf2f((unsigned short)v0[2]) + bf2f((unsigned short)v1[2]);
    a3 += bf2f((unsigned short)v0[3]) + bf2f((unsigned short)v1[3]);
  }
  if (i < en) {
    s16x4 v0 = *(const s16x4*)(MSG + (size_t)i * 256 + lane * 4);
    a0 += bf2f((unsigned short)v0[0]);
    a1 += bf2f((unsigned short)v0[1]);
    a2 += bf2f((unsigned short)v0[2]);
    a3 += bf2f((unsigned short)v0[3]);
  }
  int degc = en - i0;
  float d = (float)(degc > 1 ? degc : 1);
  float l2 = __log2f(d);
  float4 dpv = *(const float4*)(dp + lane * 4);
  float4 xr = *(const float4*)(x_res + (size_t)n * CC + lane * 4);
  float4 o;
  o.x = exp2f(l2 * dpv.x) * a0 + xr.x;
  o.y = exp2f(l2 * dpv.y) * a1 + xr.y;
  o.z = exp2f(l2 * dpv.z) * a2 + xr.z;
  o.w = exp2f(l2 * dpv.w) * a3 + xr.w;
  *(float4*)(out + (size_t)n * CC + lane * 4) = o;
}

extern "C" void kernel_launch(void* const* d_in, const int* in_sizes, int n_in,
                              void* d_out, int out_size, void* d_ws, size_t ws_size,
                              hipStream_t stream) {
  (void)in_sizes; (void)n_in; (void)out_size;
  const float* x        = (const float*)d_in[0];
  const float* x_res    = (const float*)d_in[1];
  const float* z_rw     = (const float*)d_in[2];
  const int*   ei       = (const int*)d_in[3];
  const float* w_src    = (const float*)d_in[4];
  const float* w_tgt    = (const float*)d_in[5];
  const float* w_pre    = (const float*)d_in[6];
  const float* w_gate_p = (const float*)d_in[7];
  const float* w_val_p  = (const float*)d_in[8];
  const float* w_post_p = (const float*)d_in[9];
  const float* w_gate_f = (const float*)d_in[10];
  const float* w_val_f  = (const float*)d_in[11];
  const float* w_post_f = (const float*)d_in[12];
  const float* dparam   = (const float*)d_in[13];
  float* out = (float*)d_out;

  // ---- workspace layout (256B aligned) ----
  char* W = (char*)d_ws;
  size_t off = 0;
  auto alloc = [&](size_t bytes) {
    size_t o = off;
    off = (off + bytes + 255) & ~(size_t)255;
    return o;
  };
  unsigned short* x0     = (unsigned short*)(W + alloc((size_t)NN * CC * 2));
  unsigned short* x1     = (unsigned short*)(W + alloc((size_t)NN * CC * 2));
  unsigned short* Fpre   = (unsigned short*)(W + alloc(8192 * 2));
  unsigned short* Fg_p   = (unsigned short*)(W + alloc(16384 * 2));
  unsigned short* Fv_p   = (unsigned short*)(W + alloc(16384 * 2));
  unsigned short* Fp_p   = (unsigned short*)(W + alloc(131072 * 2));
  unsigned short* Fg_f   = (unsigned short*)(W + alloc(16384 * 2));
  unsigned short* Fv_f   = (unsigned short*)(W + alloc(16384 * 2));
  unsigned short* Fp_f   = (unsigned short*)(W + alloc(131072 * 2));
  int* degi              = (int*)(W + alloc(2 * (size_t)NN * 4));  // degi+cursor
  int* cursor            = degi + NN;
  int* starts            = (int*)(W + alloc(((size_t)NN + 1) * 4));
  int* elist             = (int*)(W + alloc((size_t)NE * 4));
  size_t tail = off;
  unsigned short* MSG = (unsigned short*)(W + tail);   // NE*CC*2 = 164MB
  float* xx           = (float*)(W + tail);            // NN*CC*4 = 20.5MB (fallback)
  bool use_msg = (tail + (size_t)NE * CC * 2) <= ws_size;

  hipMemsetAsync(degi, 0, 2 * (size_t)NN * 4, stream);

  repack_kernel<<<8, 256, 0, stream>>>(w_pre, Fpre, 16, 2);
  repack_kernel<<<16, 256, 0, stream>>>(w_gate_p, Fg_p, 32, 2);
  repack_kernel<<<16, 256, 0, stream>>>(w_val_p, Fv_p, 32, 2);
  repack_kernel<<<128, 256, 0, stream>>>(w_post_p, Fp_p, 16, 32);
  repack_kernel<<<16, 256, 0, stream>>>(w_gate_f, Fg_f, 32, 2);
  repack_kernel<<<16, 256, 0, stream>>>(w_val_f, Fv_f, 32, 2);
  repack_kernel<<<128, 256, 0, stream>>>(w_post_f, Fp_f, 16, 32);

  proj_kernel<<<dim3(NN / 32, 2), 256, 0, stream>>>(x, w_src, w_tgt, x0, x1);
  deg_int_kernel<<<(NE + 255) / 256, 256, 0, stream>>>(ei, degi);

  if (use_msg) {
    prefix_kernel<<<1, 64, 0, stream>>>(degi, starts);
    fill_kernel<<<(NE + 255) / 256, 256, 0, stream>>>(ei, starts, cursor, elist);
    edge_fused<0><<<NE / 64, 256, 0, stream>>>(x0, x1, z_rw, ei, elist, starts,
                                               Fpre, Fg_p, Fv_p, Fp_p,
                                               Fg_f, Fv_f, Fp_f, nullptr, MSG);
    aggregate_kernel<<<(NN + 3) / 4, 256, 0, stream>>>(MSG, starts,
                                                       dparam, x_res, out);
  } else {
    hipMemsetAsync(xx, 0, (size_t)NN * CC * 4, stream);
    edge_fused<1><<<NE / 64, 256, 0, stream>>>(x0, x1, z_rw, ei, elist, starts,
                                               Fpre, Fg_p, Fv_p, Fp_p,
                                               Fg_f, Fv_f, Fp_f, xx, nullptr);
    finalize_kernel<<<(NN * CC + 255) / 256, 256, 0, stream>>>(xx, degi, dparam,
                                                               x_res, out);
  }
}

// Round 9
// 3015.711 us; speedup vs baseline: 1.8425x; 1.0037x over previous
//
#include <hip/hip_runtime.h>
#include <hip/hip_bf16.h>

// Problem constants (fixed by the reference)
#define NN   20000      // nodes
#define NE   320000     // edges
#define CC   256        // width
#define CA   512        // width_act

typedef __attribute__((ext_vector_type(4))) short s16x4;   // 4 bf16 (2 VGPRs)
typedef __attribute__((ext_vector_type(4))) float f32x4;   // MFMA accumulator

__device__ __forceinline__ unsigned short f2bf(float f) {
  unsigned int u = __float_as_uint(f);
  u += 0x7fff + ((u >> 16) & 1);          // RNE
  return (unsigned short)(u >> 16);
}
__device__ __forceinline__ float bf2f(unsigned short h) {
  return __uint_as_float(((unsigned int)h) << 16);
}

// K=16 bf16 MFMA: operand frag (A or B): elem j = M[row=lane&15][k=(lane>>4)*4+j].
// D: col = lane&15 (N), row = (lane>>4)*4 + reg (M).  (validated rounds 4/6/7/8)
#if defined(__has_builtin)
#if __has_builtin(__builtin_amdgcn_mfma_f32_16x16x16bf16_1k)
#define HAVE_MFMA1K 1
#endif
#endif
__device__ __forceinline__ f32x4 MFMA16(s16x4 a, s16x4 b, f32x4 c) {
#ifdef HAVE_MFMA1K
  return __builtin_amdgcn_mfma_f32_16x16x16bf16_1k(a, b, c, 0, 0, 0);
#else
  f32x4 d;
  asm volatile("v_mfma_f32_16x16x16_bf16 %0, %1, %2, %3"
               : "=&v"(d) : "v"(a), "v"(b), "v"(c));
  return d;
#endif
}

__device__ __forceinline__ s16x4 FR(const unsigned short* base, int f, int lane) {
  return *(const s16x4*)(base + (size_t)f * 256 + lane * 4);
}
__device__ __forceinline__ s16x4 pack4(f32x4 v) {
  s16x4 o;
  #pragma unroll
  for (int j = 0; j < 4; j++) o[j] = (short)f2bf(v[j]);
  return o;
}
__device__ __forceinline__ f32x4 up4(s16x4 v) {
  f32x4 o;
  #pragma unroll
  for (int j = 0; j < 4; j++) o[j] = bf2f((unsigned short)v[j]);
  return o;
}
// swizzled byte offset within the [64][512B] LDS msg buffer (bijective per row)
__device__ __forceinline__ int msws(int row, int b) {
  return row * 512 + (b ^ ((row & 7) << 4));
}

// ---- repack weights [O][K] f32 -> frag-major bf16 ----
__global__ void repack_kernel(const float* __restrict__ src,
                              unsigned short* __restrict__ dst,
                              int OT, int KT) {
  int g = blockIdx.x * 256 + threadIdx.x;
  if (g >= OT * KT * 64) return;
  int lane = g & 63, f = g >> 6;
  int kt = f / OT, ot = f - kt * OT;
  int el = lane & 15, q = lane >> 4;
  const float* s = src + (size_t)(ot * 16 + el) * (KT * 16) + kt * 16 + q * 4;
  unsigned short* d = dst + (size_t)f * 256 + lane * 4;
  d[0] = f2bf(s[0]); d[1] = f2bf(s[1]); d[2] = f2bf(s[2]); d[3] = f2bf(s[3]);
}

__global__ __launch_bounds__(256) void proj_kernel(
    const float* __restrict__ x, const float* __restrict__ w_src,
    const float* __restrict__ w_tgt, unsigned short* __restrict__ x0,
    unsigned short* __restrict__ x1) {
  __shared__ float xs[32 * 256];
  const int tid = threadIdx.x;
  const int row0 = blockIdx.x * 32;
  const float* w = blockIdx.y ? w_tgt : w_src;
  unsigned short* out = blockIdx.y ? x1 : x0;

  const float4* src = (const float4*)(x + (size_t)row0 * CC);
  float4* dstv = (float4*)xs;
  for (int i = tid; i < 2048; i += 256) dstv[i] = src[i];
  __syncthreads();

  const int c = tid;
  float acc[32];
  #pragma unroll
  for (int r = 0; r < 32; r++) acc[r] = 0.f;
  for (int k = 0; k < 256; k += 4) {
    float4 wv = *(const float4*)(w + (size_t)c * CC + k);
    #pragma unroll
    for (int r = 0; r < 32; r++) {
      float4 xv = *(const float4*)(&xs[r * 256 + k]);
      acc[r] += xv.x * wv.x + xv.y * wv.y + xv.z * wv.z + xv.w * wv.w;
    }
  }
  #pragma unroll
  for (int r = 0; r < 32; r++) out[(size_t)(row0 + r) * CC + c] = f2bf(acc[r]);
}

__global__ void deg_int_kernel(const int* __restrict__ ei, int* __restrict__ degi) {
  int e = blockIdx.x * blockDim.x + threadIdx.x;
  if (e >= NE) return;
  int k0 = ei[e], k1 = ei[NE + e];
  if (k0 != k1) atomicAdd(&degi[k1], 1);
}

__global__ __launch_bounds__(64) void prefix_kernel(const int* __restrict__ degi,
                                                    int* __restrict__ starts) {
  int lane = threadIdx.x;
  int runoff = 0;
  for (int base = 0; base < NN; base += 64) {
    int v = (base + lane < NN) ? degi[base + lane] : 0;
    int s = v;
    #pragma unroll
    for (int o = 1; o < 64; o <<= 1) {
      int x = __shfl_up(s, o);
      if (lane >= o) s += x;
    }
    if (base + lane < NN) starts[base + lane] = runoff + s - v;
    runoff += __shfl(s, 63);
  }
  if (lane == 0) starts[NN] = runoff;
}

__global__ void fill_kernel(const int* __restrict__ ei, const int* __restrict__ starts,
                            int* __restrict__ cursor, int* __restrict__ elist) {
  int e = blockIdx.x * blockDim.x + threadIdx.x;
  if (e >= NE) return;
  int k0 = ei[e], k1 = ei[NE + e];
  if (k0 != k1) {
    int p = atomicAdd(&cursor[k1], 1);
    elist[starts[k1] + p] = e;
  }
}

// ---------------- fused all-register edge kernel ----------------
// Block = 4 waves = 2 tile-pairs x 2 c-halves; 64 CSR slots per block.
// ALL global accesses are full-512B-row-per-instruction (R3's empirically
// amplification-free shape): msg gather staged to LDS at kernel start,
// msg result transposed through LDS and stored row-contiguous. No atomics.
__global__ __launch_bounds__(256, 2) void edge_fused(
    const unsigned short* __restrict__ x0g, const unsigned short* __restrict__ x1g,
    const float* __restrict__ z_rw, const int* __restrict__ ei,
    const int* __restrict__ elist, const int* __restrict__ starts,
    const unsigned short* __restrict__ Fpre,
    const unsigned short* __restrict__ Fg_p, const unsigned short* __restrict__ Fv_p,
    const unsigned short* __restrict__ Fp_p,
    const unsigned short* __restrict__ Fg_f, const unsigned short* __restrict__ Fv_f,
    const unsigned short* __restrict__ Fp_f,
    unsigned short* __restrict__ MSG) {
  __shared__ char MSb[64 * 512];        // 32 KB msg rows bf16, XOR-swizzled
  __shared__ s16x4 BLDS[4][16][64];     // 32 KB bias frag exchange
  __shared__ float ST[64][20];          // 5 KB GN stats (mu,ri at h*2), padded
  __shared__ int K0s[64], K1s[64];

  const int tid = threadIdx.x;
  const int lane = tid & 63;
  const int w = tid >> 6;
  const int el = lane & 15, q = lane >> 4;
  const int chalf = w & 1;              // post output-channel half
  const int tp = w >> 1;                // tile-pair 0/1
  const int sbase = blockIdx.x * 64;
  const f32x4 zero4 = {0.f, 0.f, 0.f, 0.f};
  const int nv = starts[NN];            // number of valid (non-self) edges

  if (tid < 64) {
    int slot = sbase + tid;
    int e = elist[slot < nv ? slot : 0];
    K0s[tid] = ei[e];
    K1s[tid] = ei[NE + e];
  }
  __syncthreads();                      // B1

  // ---- stage msg rows (wave w owns rows w*16..w*16+15): one full 512B row
  //      per global load instruction; fp32 GN stats via 8-lane shuffles ----
  #pragma unroll 4
  for (int i = 0; i < 16; i++) {
    int row = w * 16 + i;
    int kk0 = K0s[row], kk1 = K1s[row];
    s16x4 a = *(const s16x4*)(x0g + (size_t)kk0 * 256 + lane * 4);
    s16x4 b = *(const s16x4*)(x1g + (size_t)kk1 * 256 + lane * 4);
    f32x4 m;
    #pragma unroll
    for (int j = 0; j < 4; j++)
      m[j] = bf2f((unsigned short)a[j]) + bf2f((unsigned short)b[j]);
    float s1 = m[0] + m[1] + m[2] + m[3];
    float s2 = m[0]*m[0] + m[1]*m[1] + m[2]*m[2] + m[3]*m[3];
    s1 += __shfl_xor(s1, 1); s1 += __shfl_xor(s1, 2); s1 += __shfl_xor(s1, 4);
    s2 += __shfl_xor(s2, 1); s2 += __shfl_xor(s2, 2); s2 += __shfl_xor(s2, 4);
    if ((lane & 7) == 0) {
      float mu = s1 * (1.f / 32.f);
      float var = fmaxf(s2 * (1.f / 32.f) - mu * mu, 0.f);
      ST[row][(lane >> 3) * 2]     = mu;
      ST[row][(lane >> 3) * 2 + 1] = rsqrtf(var + 1e-5f);
    }
    *(s16x4*)(MSb + msws(row, lane * 8)) = pack4(m);
  }

  // ---- perw block (z-based, per-h fused; unchanged from round 8) ----
  int k0[2], k1[2];
  #pragma unroll
  for (int t = 0; t < 2; t++) {
    k0[t] = K0s[tp * 32 + t * 16 + el];
    k1[t] = K1s[tp * 32 + t * 16 + el];
  }
  s16x4 bz0[2], bz1[2];
  #pragma unroll
  for (int t = 0; t < 2; t++) {
    float4 a = *(const float4*)(z_rw + (size_t)k0[t] * 16 + q * 4);
    float4 b = *(const float4*)(z_rw + (size_t)k1[t] * 16 + q * 4);
    bz0[t][0] = (short)f2bf(a.x); bz0[t][1] = (short)f2bf(a.y);
    bz0[t][2] = (short)f2bf(a.z); bz0[t][3] = (short)f2bf(a.w);
    bz1[t][0] = (short)f2bf(b.x); bz1[t][1] = (short)f2bf(b.y);
    bz1[t][2] = (short)f2bf(b.z); bz1[t][3] = (short)f2bf(b.w);
  }

  f32x4 acc[2][8];
  #pragma unroll
  for (int t = 0; t < 2; t++)
    #pragma unroll
    for (int c8 = 0; c8 < 8; c8++) acc[t][c8] = zero4;

  #pragma unroll
  for (int h = 0; h < 8; h++) {
    f32x4 pr[2][2];
    #pragma unroll
    for (int mt2 = 0; mt2 < 2; mt2++) {
      int mt = 2 * h + mt2;
      s16x4 fa0 = FR(Fpre, mt, lane);
      s16x4 fa1 = FR(Fpre, 16 + mt, lane);
      #pragma unroll
      for (int t = 0; t < 2; t++) {
        f32x4 d = MFMA16(fa0, bz0[t], zero4);
        pr[t][mt2] = MFMA16(fa1, bz1[t], d);
      }
    }
    s16x4 t16[2][2];
    #pragma unroll
    for (int t = 0; t < 2; t++) {
      float s1 = 0.f, s2 = 0.f;
      #pragma unroll
      for (int mt2 = 0; mt2 < 2; mt2++)
        #pragma unroll
        for (int j = 0; j < 4; j++) {
          float v = pr[t][mt2][j];
          s1 += v; s2 += v * v;
        }
      s1 += __shfl_xor(s1, 16); s1 += __shfl_xor(s1, 32);
      s2 += __shfl_xor(s2, 16); s2 += __shfl_xor(s2, 32);
      float mu = s1 * (1.f / 32.f);
      float var = fmaxf(s2 * (1.f / 32.f) - mu * mu, 0.f);
      float ri = rsqrtf(var + 1e-5f);
      #pragma unroll
      for (int mt2 = 0; mt2 < 2; mt2++) {
        f32x4 n;
        #pragma unroll
        for (int j = 0; j < 4; j++) n[j] = (pr[t][mt2][j] - mu) * ri;
        t16[t][mt2] = pack4(n);
      }
    }
    #pragma unroll
    for (int ot = 0; ot < 4; ot++) {
      int kpc = h * 4 + ot;
      s16x4 fg0 = FR(Fg_p, kpc, lane), fg1 = FR(Fg_p, 32 + kpc, lane);
      s16x4 fv0 = FR(Fv_p, kpc, lane), fv1 = FR(Fv_p, 32 + kpc, lane);
      s16x4 u[2];
      #pragma unroll
      for (int t = 0; t < 2; t++) {
        f32x4 g = MFMA16(fg0, t16[t][0], zero4);
        g = MFMA16(fg1, t16[t][1], g);
        f32x4 v = MFMA16(fv0, t16[t][0], zero4);
        v = MFMA16(fv1, t16[t][1], v);
        f32x4 uf;
        #pragma unroll
        for (int j = 0; j < 4; j++) uf[j] = fmaxf(g[j], 0.f) * v[j];
        u[t] = pack4(uf);
      }
      #pragma unroll
      for (int c8 = 0; c8 < 8; c8++) {
        s16x4 fp = FR(Fp_p, kpc * 16 + chalf * 8 + c8, lane);
        #pragma unroll
        for (int t = 0; t < 2; t++)
          acc[t][c8] = MFMA16(fp, u[t], acc[t][c8]);   // D rows = out-ch
      }
    }
  }

  // ---- bias exchange ----
  #pragma unroll
  for (int t = 0; t < 2; t++)
    #pragma unroll
    for (int c8 = 0; c8 < 8; c8++)
      BLDS[tp * 2 + t][chalf * 8 + c8][lane] = pack4(acc[t][c8]);
  __syncthreads();                      // B2 (covers MS staging + BLDS)

  // ---- ffn block: msg frags from LDS ----
  #pragma unroll
  for (int t = 0; t < 2; t++)
    #pragma unroll
    for (int c8 = 0; c8 < 8; c8++) acc[t][c8] = zero4;

  #pragma unroll
  for (int h = 0; h < 8; h++) {
    s16x4 tv16[2][2], tg16[2][2];
    #pragma unroll
    for (int t = 0; t < 2; t++) {
      int row = tp * 32 + t * 16 + el;
      float mu = ST[row][h * 2], ri = ST[row][h * 2 + 1];
      f32x4 nm[2];
      #pragma unroll
      for (int mt2 = 0; mt2 < 2; mt2++) {
        int mt = 2 * h + mt2;
        s16x4 raw = *(const s16x4*)(MSb + msws(row, mt * 32 + q * 8));
        #pragma unroll
        for (int j = 0; j < 4; j++)
          nm[mt2][j] = (bf2f((unsigned short)raw[j]) - mu) * ri;
        tv16[t][mt2] = pack4(nm[mt2]);
      }
      f32x4 bb0 = up4(BLDS[tp * 2 + t][2 * h][lane]);
      f32x4 bb1 = up4(BLDS[tp * 2 + t][2 * h + 1][lane]);
      f32x4 g0, g1;
      #pragma unroll
      for (int j = 0; j < 4; j++) {
        g0[j] = nm[0][j] + bb0[j];
        g1[j] = nm[1][j] + bb1[j];
      }
      tg16[t][0] = pack4(g0);
      tg16[t][1] = pack4(g1);
    }
    #pragma unroll
    for (int ot = 0; ot < 4; ot++) {
      int kpc = h * 4 + ot;
      s16x4 fg0 = FR(Fg_f, kpc, lane), fg1 = FR(Fg_f, 32 + kpc, lane);
      s16x4 fv0 = FR(Fv_f, kpc, lane), fv1 = FR(Fv_f, 32 + kpc, lane);
      s16x4 u[2];
      #pragma unroll
      for (int t = 0; t < 2; t++) {
        f32x4 g = MFMA16(fg0, tg16[t][0], zero4);
        g = MFMA16(fg1, tg16[t][1], g);
        f32x4 v = MFMA16(fv0, tv16[t][0], zero4);
        v = MFMA16(fv1, tv16[t][1], v);
        f32x4 uf;
        #pragma unroll
        for (int j = 0; j < 4; j++) uf[j] = fmaxf(g[j], 0.f) * v[j];
        u[t] = pack4(uf);
      }
      #pragma unroll
      for (int c8 = 0; c8 < 8; c8++) {
        s16x4 fb = FR(Fp_f, kpc * 16 + chalf * 8 + c8, lane);
        #pragma unroll
        for (int t = 0; t < 2; t++)
          acc[t][c8] = MFMA16(fb, u[t], acc[t][c8]);   // D rows = out-ch
      }
    }
  }
  __syncthreads();                      // B3: all MS/BLDS reads done

  // ---- transpose acc through LDS (reuse MSb) ----
  // lane (el,q) reg r holds channel chalf*128 + c8*16 + q*4 + r of row
  #pragma unroll
  for (int t = 0; t < 2; t++) {
    int row = tp * 32 + t * 16 + el;
    #pragma unroll
    for (int c8 = 0; c8 < 8; c8++)
      *(s16x4*)(MSb + msws(row, chalf * 256 + c8 * 32 + q * 8)) =
          pack4(acc[t][c8]);
  }
  __syncthreads();                      // B4

  // ---- coalesced store: one full 512B MSG row per instruction ----
  #pragma unroll 4
  for (int i = 0; i < 16; i++) {
    int row = w * 16 + i;
    int slot = sbase + row;
    if (slot < nv) {
      s16x4 v = *(const s16x4*)(MSb + msws(row, lane * 8));
      *(s16x4*)(MSG + (size_t)slot * 256 + lane * 4) = v;
    }
  }
}

// per-node aggregation over CONTIGUOUS slots + degree-power + residual
__global__ __launch_bounds__(256) void aggregate_kernel(
    const unsigned short* __restrict__ MSG, const int* __restrict__ starts,
    const float* __restrict__ dp, const float* __restrict__ x_res,
    float* __restrict__ out) {
  int wid = threadIdx.x >> 6, lane = threadIdx.x & 63;
  int n = blockIdx.x * 4 + wid;
  if (n >= NN) return;
  int i0 = starts[n], en = starts[n + 1];
  float a0 = 0.f, a1 = 0.f, a2 = 0.f, a3 = 0.f;
  int i = i0;
  for (; i + 2 <= en; i += 2) {
    s16x4 v0 = *(const s16x4*)(MSG + (size_t)i * 256 + lane * 4);
    s16x4 v1 = *(const s16x4*)(MSG + (size_t)(i + 1) * 256 + lane * 4);
    a0 += bf2f((unsigned short)v0[0]) + bf2f((unsigned short)v1[0]);
    a1 += bf2f((unsigned short)v0[1]) + bf2f((unsigned short)v1[1]);
    a2 += bf2f((unsigned short)v0[2]) + bf2f((unsigned short)v1[2]);
    a3 += bf2f((unsigned short)v0[3]) + bf2f((unsigned short)v1[3]);
  }
  if (i < en) {
    s16x4 v0 = *(const s16x4*)(MSG + (size_t)i * 256 + lane * 4);
    a0 += bf2f((unsigned short)v0[0]);
    a1 += bf2f((unsigned short)v0[1]);
    a2 += bf2f((unsigned short)v0[2]);
    a3 += bf2f((unsigned short)v0[3]);
  }
  int degc = en - i0;
  float d = (float)(degc > 1 ? degc : 1);
  float l2 = __log2f(d);
  float4 dpv = *(const float4*)(dp + lane * 4);
  float4 xr = *(const float4*)(x_res + (size_t)n * CC + lane * 4);
  float4 o;
  o.x = exp2f(l2 * dpv.x) * a0 + xr.x;
  o.y = exp2f(l2 * dpv.y) * a1 + xr.y;
  o.z = exp2f(l2 * dpv.z) * a2 + xr.z;
  o.w = exp2f(l2 * dpv.w) * a3 + xr.w;
  *(float4*)(out + (size_t)n * CC + lane * 4) = o;
}

extern "C" void kernel_launch(void* const* d_in, const int* in_sizes, int n_in,
                              void* d_out, int out_size, void* d_ws, size_t ws_size,
                              hipStream_t stream) {
  (void)in_sizes; (void)n_in; (void)out_size; (void)ws_size;
  const float* x        = (const float*)d_in[0];
  const float* x_res    = (const float*)d_in[1];
  const float* z_rw     = (const float*)d_in[2];
  const int*   ei       = (const int*)d_in[3];
  const float* w_src    = (const float*)d_in[4];
  const float* w_tgt    = (const float*)d_in[5];
  const float* w_pre    = (const float*)d_in[6];
  const float* w_gate_p = (const float*)d_in[7];
  const float* w_val_p  = (const float*)d_in[8];
  const float* w_post_p = (const float*)d_in[9];
  const float* w_gate_f = (const float*)d_in[10];
  const float* w_val_f  = (const float*)d_in[11];
  const float* w_post_f = (const float*)d_in[12];
  const float* dparam   = (const float*)d_in[13];
  float* out = (float*)d_out;

  // ---- workspace layout (256B aligned) ----
  char* W = (char*)d_ws;
  size_t off = 0;
  auto alloc = [&](size_t bytes) {
    size_t o = off;
    off = (off + bytes + 255) & ~(size_t)255;
    return o;
  };
  unsigned short* x0     = (unsigned short*)(W + alloc((size_t)NN * CC * 2));
  unsigned short* x1     = (unsigned short*)(W + alloc((size_t)NN * CC * 2));
  unsigned short* Fpre   = (unsigned short*)(W + alloc(8192 * 2));
  unsigned short* Fg_p   = (unsigned short*)(W + alloc(16384 * 2));
  unsigned short* Fv_p   = (unsigned short*)(W + alloc(16384 * 2));
  unsigned short* Fp_p   = (unsigned short*)(W + alloc(131072 * 2));
  unsigned short* Fg_f   = (unsigned short*)(W + alloc(16384 * 2));
  unsigned short* Fv_f   = (unsigned short*)(W + alloc(16384 * 2));
  unsigned short* Fp_f   = (unsigned short*)(W + alloc(131072 * 2));
  int* degi              = (int*)(W + alloc(2 * (size_t)NN * 4));  // degi+cursor
  int* cursor            = degi + NN;
  int* starts            = (int*)(W + alloc(((size_t)NN + 1) * 4));
  int* elist             = (int*)(W + alloc((size_t)NE * 4));
  unsigned short* MSG    = (unsigned short*)(W + alloc((size_t)NE * CC * 2));

  hipMemsetAsync(degi, 0, 2 * (size_t)NN * 4, stream);

  repack_kernel<<<8, 256, 0, stream>>>(w_pre, Fpre, 16, 2);
  repack_kernel<<<16, 256, 0, stream>>>(w_gate_p, Fg_p, 32, 2);
  repack_kernel<<<16, 256, 0, stream>>>(w_val_p, Fv_p, 32, 2);
  repack_kernel<<<128, 256, 0, stream>>>(w_post_p, Fp_p, 16, 32);
  repack_kernel<<<16, 256, 0, stream>>>(w_gate_f, Fg_f, 32, 2);
  repack_kernel<<<16, 256, 0, stream>>>(w_val_f, Fv_f, 32, 2);
  repack_kernel<<<128, 256, 0, stream>>>(w_post_f, Fp_f, 16, 32);

  proj_kernel<<<dim3(NN / 32, 2), 256, 0, stream>>>(x, w_src, w_tgt, x0, x1);
  deg_int_kernel<<<(NE + 255) / 256, 256, 0, stream>>>(ei, degi);
  prefix_kernel<<<1, 64, 0, stream>>>(degi, starts);
  fill_kernel<<<(NE + 255) / 256, 256, 0, stream>>>(ei, starts, cursor, elist);

  edge_fused<<<NE / 64, 256, 0, stream>>>(x0, x1, z_rw, ei, elist, starts,
                                          Fpre, Fg_p, Fv_p, Fp_p,
                                          Fg_f, Fv_f, Fp_f, MSG);
  aggregate_kernel<<<(NN + 3) / 4, 256, 0, stream>>>(MSG, starts,
                                                     dparam, x_res, out);
}

// Round 10
// 2012.841 us; speedup vs baseline: 2.7604x; 1.4982x over previous
//
#include <hip/hip_runtime.h>
#include <hip/hip_bf16.h>

// Problem constants (fixed by the reference)
#define NN   20000      // nodes
#define NE   320000     // edges
#define CC   256        // width
#define CA   512        // width_act

typedef __attribute__((ext_vector_type(4))) short s16x4;   // 4 bf16 (2 VGPRs)
typedef __attribute__((ext_vector_type(4))) float f32x4;   // MFMA accumulator

__device__ __forceinline__ unsigned short f2bf(float f) {
  unsigned int u = __float_as_uint(f);
  u += 0x7fff + ((u >> 16) & 1);          // RNE
  return (unsigned short)(u >> 16);
}
__device__ __forceinline__ float bf2f(unsigned short h) {
  return __uint_as_float(((unsigned int)h) << 16);
}

// K=16 bf16 MFMA: operand frag (A or B): elem j = M[row=lane&15][k=(lane>>4)*4+j].
// D: col = lane&15 (N), row = (lane>>4)*4 + reg (M).  (validated rounds 4/6-9)
#if defined(__has_builtin)
#if __has_builtin(__builtin_amdgcn_mfma_f32_16x16x16bf16_1k)
#define HAVE_MFMA1K 1
#endif
#endif
__device__ __forceinline__ f32x4 MFMA16(s16x4 a, s16x4 b, f32x4 c) {
#ifdef HAVE_MFMA1K
  return __builtin_amdgcn_mfma_f32_16x16x16bf16_1k(a, b, c, 0, 0, 0);
#else
  f32x4 d;
  asm volatile("v_mfma_f32_16x16x16_bf16 %0, %1, %2, %3"
               : "=&v"(d) : "v"(a), "v"(b), "v"(c));
  return d;
#endif
}

__device__ __forceinline__ s16x4 FR(const unsigned short* base, int f, int lane) {
  return *(const s16x4*)(base + (size_t)f * 256 + lane * 4);
}
__device__ __forceinline__ s16x4 pack4(f32x4 v) {
  s16x4 o;
  #pragma unroll
  for (int j = 0; j < 4; j++) o[j] = (short)f2bf(v[j]);
  return o;
}
__device__ __forceinline__ f32x4 up4(s16x4 v) {
  f32x4 o;
  #pragma unroll
  for (int j = 0; j < 4; j++) o[j] = bf2f((unsigned short)v[j]);
  return o;
}
// swizzled byte offset within the [64][512B] LDS msg buffer (bijective per row)
__device__ __forceinline__ int msws(int row, int b) {
  return row * 512 + (b ^ ((row & 7) << 4));
}

// ---- repack weights [O][K] f32 -> frag-major bf16 ----
__global__ void repack_kernel(const float* __restrict__ src,
                              unsigned short* __restrict__ dst,
                              int OT, int KT) {
  int g = blockIdx.x * 256 + threadIdx.x;
  if (g >= OT * KT * 64) return;
  int lane = g & 63, f = g >> 6;
  int kt = f / OT, ot = f - kt * OT;
  int el = lane & 15, q = lane >> 4;
  const float* s = src + (size_t)(ot * 16 + el) * (KT * 16) + kt * 16 + q * 4;
  unsigned short* d = dst + (size_t)f * 256 + lane * 4;
  d[0] = f2bf(s[0]); d[1] = f2bf(s[1]); d[2] = f2bf(s[2]); d[3] = f2bf(s[3]);
}

__global__ __launch_bounds__(256) void proj_kernel(
    const float* __restrict__ x, const float* __restrict__ w_src,
    const float* __restrict__ w_tgt, unsigned short* __restrict__ x0,
    unsigned short* __restrict__ x1) {
  __shared__ float xs[32 * 256];
  const int tid = threadIdx.x;
  const int row0 = blockIdx.x * 32;
  const float* w = blockIdx.y ? w_tgt : w_src;
  unsigned short* out = blockIdx.y ? x1 : x0;

  const float4* src = (const float4*)(x + (size_t)row0 * CC);
  float4* dstv = (float4*)xs;
  for (int i = tid; i < 2048; i += 256) dstv[i] = src[i];
  __syncthreads();

  const int c = tid;
  float acc[32];
  #pragma unroll
  for (int r = 0; r < 32; r++) acc[r] = 0.f;
  for (int k = 0; k < 256; k += 4) {
    float4 wv = *(const float4*)(w + (size_t)c * CC + k);
    #pragma unroll
    for (int r = 0; r < 32; r++) {
      float4 xv = *(const float4*)(&xs[r * 256 + k]);
      acc[r] += xv.x * wv.x + xv.y * wv.y + xv.z * wv.z + xv.w * wv.w;
    }
  }
  #pragma unroll
  for (int r = 0; r < 32; r++) out[(size_t)(row0 + r) * CC + c] = f2bf(acc[r]);
}

__global__ void deg_int_kernel(const int* __restrict__ ei, int* __restrict__ degi) {
  int e = blockIdx.x * blockDim.x + threadIdx.x;
  if (e >= NE) return;
  int k0 = ei[e], k1 = ei[NE + e];
  if (k0 != k1) atomicAdd(&degi[k1], 1);
}

__global__ __launch_bounds__(64) void prefix_kernel(const int* __restrict__ degi,
                                                    int* __restrict__ starts) {
  int lane = threadIdx.x;
  int runoff = 0;
  for (int base = 0; base < NN; base += 64) {
    int v = (base + lane < NN) ? degi[base + lane] : 0;
    int s = v;
    #pragma unroll
    for (int o = 1; o < 64; o <<= 1) {
      int x = __shfl_up(s, o);
      if (lane >= o) s += x;
    }
    if (base + lane < NN) starts[base + lane] = runoff + s - v;
    runoff += __shfl(s, 63);
  }
  if (lane == 0) starts[NN] = runoff;
}

__global__ void fill_kernel(const int* __restrict__ ei, const int* __restrict__ starts,
                            int* __restrict__ cursor, int* __restrict__ elist) {
  int e = blockIdx.x * blockDim.x + threadIdx.x;
  if (e >= NE) return;
  int k0 = ei[e], k1 = ei[NE + e];
  if (k0 != k1) {
    int p = atomicAdd(&cursor[k1], 1);
    elist[starts[k1] + p] = e;
  }
}

// ---------------- fused edge kernel, spill-free sizing ----------------
// 512 threads = 8 waves = 4 edge-tiles x 2 c-halves; 64 CSR slots/block.
// Wave owns ONE 16-edge tile and half the post channels: acc[8] = 32 VGPRs.
// h-loops kept ROLLED to bound register pressure (spills were the hidden
// multi-GB HBM traffic in rounds 4-9). All global accesses full-512B-row.
__global__ __launch_bounds__(512, 4) void edge_fused(
    const unsigned short* __restrict__ x0g, const unsigned short* __restrict__ x1g,
    const float* __restrict__ z_rw, const int* __restrict__ ei,
    const int* __restrict__ elist, const int* __restrict__ starts,
    const unsigned short* __restrict__ Fpre,
    const unsigned short* __restrict__ Fg_p, const unsigned short* __restrict__ Fv_p,
    const unsigned short* __restrict__ Fp_p,
    const unsigned short* __restrict__ Fg_f, const unsigned short* __restrict__ Fv_f,
    const unsigned short* __restrict__ Fp_f,
    unsigned short* __restrict__ MSG) {
  __shared__ char MSb[64 * 512];        // 32 KB msg rows bf16, XOR-swizzled
  __shared__ s16x4 BLDS[4][16][64];     // 32 KB bias frag exchange
  __shared__ float ST[64][20];          // 5 KB GN stats (mu,ri at h*2)
  __shared__ int K0s[64], K1s[64];

  const int tid = threadIdx.x;
  const int lane = tid & 63;
  const int w = tid >> 6;               // wave 0..7
  const int el = lane & 15, q = lane >> 4;
  const int chalf = w & 1;              // post output-channel half
  const int tp = w >> 1;                // edge tile 0..3
  const int sbase = blockIdx.x * 64;
  const f32x4 zero4 = {0.f, 0.f, 0.f, 0.f};
  const int nv = starts[NN];

  if (tid < 64) {
    int slot = sbase + tid;
    int e = elist[slot < nv ? slot : 0];
    K0s[tid] = ei[e];
    K1s[tid] = ei[NE + e];
  }
  __syncthreads();                      // B1

  // ---- stage msg rows (wave w owns rows w*8..w*8+7): one full 512B row
  //      per global load instruction; fp32 GN stats via 8-lane shuffles ----
  #pragma unroll 4
  for (int i = 0; i < 8; i++) {
    int row = w * 8 + i;
    s16x4 a = *(const s16x4*)(x0g + (size_t)K0s[row] * 256 + lane * 4);
    s16x4 b = *(const s16x4*)(x1g + (size_t)K1s[row] * 256 + lane * 4);
    f32x4 m;
    #pragma unroll
    for (int j = 0; j < 4; j++)
      m[j] = bf2f((unsigned short)a[j]) + bf2f((unsigned short)b[j]);
    float s1 = m[0] + m[1] + m[2] + m[3];
    float s2 = m[0]*m[0] + m[1]*m[1] + m[2]*m[2] + m[3]*m[3];
    s1 += __shfl_xor(s1, 1); s1 += __shfl_xor(s1, 2); s1 += __shfl_xor(s1, 4);
    s2 += __shfl_xor(s2, 1); s2 += __shfl_xor(s2, 2); s2 += __shfl_xor(s2, 4);
    if ((lane & 7) == 0) {
      float mu = s1 * (1.f / 32.f);
      float var = fmaxf(s2 * (1.f / 32.f) - mu * mu, 0.f);
      ST[row][(lane >> 3) * 2]     = mu;
      ST[row][(lane >> 3) * 2 + 1] = rsqrtf(var + 1e-5f);
    }
    *(s16x4*)(MSb + msws(row, lane * 8)) = pack4(m);
  }

  // ---- perw block: this wave's 16 edges (rows tp*16..+15) ----
  const int k0 = K0s[tp * 16 + el];
  const int k1 = K1s[tp * 16 + el];
  s16x4 bz0, bz1;
  {
    float4 a = *(const float4*)(z_rw + (size_t)k0 * 16 + q * 4);
    float4 b = *(const float4*)(z_rw + (size_t)k1 * 16 + q * 4);
    bz0[0] = (short)f2bf(a.x); bz0[1] = (short)f2bf(a.y);
    bz0[2] = (short)f2bf(a.z); bz0[3] = (short)f2bf(a.w);
    bz1[0] = (short)f2bf(b.x); bz1[1] = (short)f2bf(b.y);
    bz1[2] = (short)f2bf(b.z); bz1[3] = (short)f2bf(b.w);
  }

  f32x4 acc[8];
  #pragma unroll
  for (int c8 = 0; c8 < 8; c8++) acc[c8] = zero4;

  for (int h = 0; h < 8; h++) {         // rolled: bounds register pressure
    f32x4 pr[2];
    #pragma unroll
    for (int mt2 = 0; mt2 < 2; mt2++) {
      int mt = 2 * h + mt2;
      f32x4 d = MFMA16(FR(Fpre, mt, lane), bz0, zero4);
      pr[mt2] = MFMA16(FR(Fpre, 16 + mt, lane), bz1, d);
    }
    float s1 = 0.f, s2 = 0.f;
    #pragma unroll
    for (int mt2 = 0; mt2 < 2; mt2++)
      #pragma unroll
      for (int j = 0; j < 4; j++) { float v = pr[mt2][j]; s1 += v; s2 += v * v; }
    s1 += __shfl_xor(s1, 16); s1 += __shfl_xor(s1, 32);
    s2 += __shfl_xor(s2, 16); s2 += __shfl_xor(s2, 32);
    float mu = s1 * (1.f / 32.f);
    float var = fmaxf(s2 * (1.f / 32.f) - mu * mu, 0.f);
    float ri = rsqrtf(var + 1e-5f);
    s16x4 t16[2];
    #pragma unroll
    for (int mt2 = 0; mt2 < 2; mt2++) {
      f32x4 n;
      #pragma unroll
      for (int j = 0; j < 4; j++) n[j] = (pr[mt2][j] - mu) * ri;
      t16[mt2] = pack4(n);
    }
    for (int ot = 0; ot < 4; ot++) {
      int kpc = h * 4 + ot;
      f32x4 g = MFMA16(FR(Fg_p, kpc, lane), t16[0], zero4);
      g = MFMA16(FR(Fg_p, 32 + kpc, lane), t16[1], g);
      f32x4 v = MFMA16(FR(Fv_p, kpc, lane), t16[0], zero4);
      v = MFMA16(FR(Fv_p, 32 + kpc, lane), t16[1], v);
      f32x4 uf;
      #pragma unroll
      for (int j = 0; j < 4; j++) uf[j] = fmaxf(g[j], 0.f) * v[j];
      s16x4 u = pack4(uf);
      #pragma unroll
      for (int c8 = 0; c8 < 8; c8++)
        acc[c8] = MFMA16(FR(Fp_p, kpc * 16 + chalf * 8 + c8, lane), u, acc[c8]);
    }
  }

  // ---- bias exchange ----
  #pragma unroll
  for (int c8 = 0; c8 < 8; c8++)
    BLDS[tp][chalf * 8 + c8][lane] = pack4(acc[c8]);
  __syncthreads();                      // B2 (covers MSb staging + BLDS)

  // ---- ffn block ----
  #pragma unroll
  for (int c8 = 0; c8 < 8; c8++) acc[c8] = zero4;

  const int row = tp * 16 + el;
  for (int h = 0; h < 8; h++) {         // rolled
    float mu = ST[row][h * 2], ri = ST[row][h * 2 + 1];
    s16x4 tv16[2], tg16[2];
    #pragma unroll
    for (int mt2 = 0; mt2 < 2; mt2++) {
      s16x4 raw = *(const s16x4*)(MSb + msws(row, (2 * h + mt2) * 32 + q * 8));
      f32x4 nm;
      #pragma unroll
      for (int j = 0; j < 4; j++)
        nm[j] = (bf2f((unsigned short)raw[j]) - mu) * ri;
      tv16[mt2] = pack4(nm);
      f32x4 bb = up4(BLDS[tp][2 * h + mt2][lane]);
      f32x4 gg;
      #pragma unroll
      for (int j = 0; j < 4; j++) gg[j] = nm[j] + bb[j];
      tg16[mt2] = pack4(gg);
    }
    for (int ot = 0; ot < 4; ot++) {
      int kpc = h * 4 + ot;
      f32x4 g = MFMA16(FR(Fg_f, kpc, lane), tg16[0], zero4);
      g = MFMA16(FR(Fg_f, 32 + kpc, lane), tg16[1], g);
      f32x4 v = MFMA16(FR(Fv_f, kpc, lane), tv16[0], zero4);
      v = MFMA16(FR(Fv_f, 32 + kpc, lane), tv16[1], v);
      f32x4 uf;
      #pragma unroll
      for (int j = 0; j < 4; j++) uf[j] = fmaxf(g[j], 0.f) * v[j];
      s16x4 u = pack4(uf);
      #pragma unroll
      for (int c8 = 0; c8 < 8; c8++)
        acc[c8] = MFMA16(FR(Fp_f, kpc * 16 + chalf * 8 + c8, lane), u, acc[c8]);
    }
  }
  __syncthreads();                      // B3: all MSb/BLDS reads done

  // ---- transpose acc through LDS (reuse MSb) ----
  // lane (el,q) reg r holds channel chalf*128 + c8*16 + q*4 + r of its row
  #pragma unroll
  for (int c8 = 0; c8 < 8; c8++)
    *(s16x4*)(MSb + msws(row, chalf * 256 + c8 * 32 + q * 8)) = pack4(acc[c8]);
  __syncthreads();                      // B4

  // ---- coalesced store: one full 512B MSG row per instruction ----
  #pragma unroll 4
  for (int i = 0; i < 8; i++) {
    int r2 = w * 8 + i;
    int slot = sbase + r2;
    if (slot < nv) {
      s16x4 v = *(const s16x4*)(MSb + msws(r2, lane * 8));
      *(s16x4*)(MSG + (size_t)slot * 256 + lane * 4) = v;
    }
  }
}

// per-node aggregation over CONTIGUOUS slots + degree-power + residual
__global__ __launch_bounds__(256) void aggregate_kernel(
    const unsigned short* __restrict__ MSG, const int* __restrict__ starts,
    const float* __restrict__ dp, const float* __restrict__ x_res,
    float* __restrict__ out) {
  int wid = threadIdx.x >> 6, lane = threadIdx.x & 63;
  int n = blockIdx.x * 4 + wid;
  if (n >= NN) return;
  int i0 = starts[n], en = starts[n + 1];
  float a0 = 0.f, a1 = 0.f, a2 = 0.f, a3 = 0.f;
  int i = i0;
  for (; i + 2 <= en; i += 2) {
    s16x4 v0 = *(const s16x4*)(MSG + (size_t)i * 256 + lane * 4);
    s16x4 v1 = *(const s16x4*)(MSG + (size_t)(i + 1) * 256 + lane * 4);
    a0 += bf2f((unsigned short)v0[0]) + bf2f((unsigned short)v1[0]);
    a1 += bf2f((unsigned short)v0[1]) + bf2f((unsigned short)v1[1]);
    a2 += bf2f((unsigned short)v0[2]) + bf2f((unsigned short)v1[2]);
    a3 += bf2f((unsigned short)v0[3]) + bf2f((unsigned short)v1[3]);
  }
  if (i < en) {
    s16x4 v0 = *(const s16x4*)(MSG + (size_t)i * 256 + lane * 4);
    a0 += bf2f((unsigned short)v0[0]);
    a1 += bf2f((unsigned short)v0[1]);
    a2 += bf2f((unsigned short)v0[2]);
    a3 += bf2f((unsigned short)v0[3]);
  }
  int degc = en - i0;
  float d = (float)(degc > 1 ? degc : 1);
  float l2 = __log2f(d);
  float4 dpv = *(const float4*)(dp + lane * 4);
  float4 xr = *(const float4*)(x_res + (size_t)n * CC + lane * 4);
  float4 o;
  o.x = exp2f(l2 * dpv.x) * a0 + xr.x;
  o.y = exp2f(l2 * dpv.y) * a1 + xr.y;
  o.z = exp2f(l2 * dpv.z) * a2 + xr.z;
  o.w = exp2f(l2 * dpv.w) * a3 + xr.w;
  *(float4*)(out + (size_t)n * CC + lane * 4) = o;
}

extern "C" void kernel_launch(void* const* d_in, const int* in_sizes, int n_in,
                              void* d_out, int out_size, void* d_ws, size_t ws_size,
                              hipStream_t stream) {
  (void)in_sizes; (void)n_in; (void)out_size; (void)ws_size;
  const float* x        = (const float*)d_in[0];
  const float* x_res    = (const float*)d_in[1];
  const float* z_rw     = (const float*)d_in[2];
  const int*   ei       = (const int*)d_in[3];
  const float* w_src    = (const float*)d_in[4];
  const float* w_tgt    = (const float*)d_in[5];
  const float* w_pre    = (const float*)d_in[6];
  const float* w_gate_p = (const float*)d_in[7];
  const float* w_val_p  = (const float*)d_in[8];
  const float* w_post_p = (const float*)d_in[9];
  const float* w_gate_f = (const float*)d_in[10];
  const float* w_val_f  = (const float*)d_in[11];
  const float* w_post_f = (const float*)d_in[12];
  const float* dparam   = (const float*)d_in[13];
  float* out = (float*)d_out;

  // ---- workspace layout (256B aligned) ----
  char* W = (char*)d_ws;
  size_t off = 0;
  auto alloc = [&](size_t bytes) {
    size_t o = off;
    off = (off + bytes + 255) & ~(size_t)255;
    return o;
  };
  unsigned short* x0     = (unsigned short*)(W + alloc((size_t)NN * CC * 2));
  unsigned short* x1     = (unsigned short*)(W + alloc((size_t)NN * CC * 2));
  unsigned short* Fpre   = (unsigned short*)(W + alloc(8192 * 2));
  unsigned short* Fg_p   = (unsigned short*)(W + alloc(16384 * 2));
  unsigned short* Fv_p   = (unsigned short*)(W + alloc(16384 * 2));
  unsigned short* Fp_p   = (unsigned short*)(W + alloc(131072 * 2));
  unsigned short* Fg_f   = (unsigned short*)(W + alloc(16384 * 2));
  unsigned short* Fv_f   = (unsigned short*)(W + alloc(16384 * 2));
  unsigned short* Fp_f   = (unsigned short*)(W + alloc(131072 * 2));
  int* degi              = (int*)(W + alloc(2 * (size_t)NN * 4));  // degi+cursor
  int* cursor            = degi + NN;
  int* starts            = (int*)(W + alloc(((size_t)NN + 1) * 4));
  int* elist             = (int*)(W + alloc((size_t)NE * 4));
  unsigned short* MSG    = (unsigned short*)(W + alloc((size_t)NE * CC * 2));

  hipMemsetAsync(degi, 0, 2 * (size_t)NN * 4, stream);

  repack_kernel<<<8, 256, 0, stream>>>(w_pre, Fpre, 16, 2);
  repack_kernel<<<16, 256, 0, stream>>>(w_gate_p, Fg_p, 32, 2);
  repack_kernel<<<16, 256, 0, stream>>>(w_val_p, Fv_p, 32, 2);
  repack_kernel<<<128, 256, 0, stream>>>(w_post_p, Fp_p, 16, 32);
  repack_kernel<<<16, 256, 0, stream>>>(w_gate_f, Fg_f, 32, 2);
  repack_kernel<<<16, 256, 0, stream>>>(w_val_f, Fv_f, 32, 2);
  repack_kernel<<<128, 256, 0, stream>>>(w_post_f, Fp_f, 16, 32);

  proj_kernel<<<dim3(NN / 32, 2), 256, 0, stream>>>(x, w_src, w_tgt, x0, x1);
  deg_int_kernel<<<(NE + 255) / 256, 256, 0, stream>>>(ei, degi);
  prefix_kernel<<<1, 64, 0, stream>>>(degi, starts);
  fill_kernel<<<(NE + 255) / 256, 256, 0, stream>>>(ei, starts, cursor, elist);

  edge_fused<<<NE / 64, 512, 0, stream>>>(x0, x1, z_rw, ei, elist, starts,
                                          Fpre, Fg_p, Fv_p, Fp_p,
                                          Fg_f, Fv_f, Fp_f, MSG);
  aggregate_kernel<<<(NN + 3) / 4, 256, 0, stream>>>(MSG, starts,
                                                     dparam, x_res, out);
}

// Round 11
// 1127.677 us; speedup vs baseline: 4.9272x; 1.7849x over previous
//
#include <hip/hip_runtime.h>
#include <hip/hip_bf16.h>

// Problem constants (fixed by the reference)
#define NN   20000      // nodes
#define NE   320000     // edges
#define CC   256        // width
#define CA   512        // width_act
#define WSB  43008      // 42 frags x 1KB per h-step

typedef __attribute__((ext_vector_type(4))) short s16x4;
typedef __attribute__((ext_vector_type(8))) short s16x8;   // K=32 frag (4 VGPRs)
typedef __attribute__((ext_vector_type(4))) float f32x4;

__device__ __forceinline__ unsigned short f2bf(float f) {
  unsigned int u = __float_as_uint(f);
  u += 0x7fff + ((u >> 16) & 1);          // RNE
  return (unsigned short)(u >> 16);
}
__device__ __forceinline__ float bf2f(unsigned short h) {
  return __uint_as_float(((unsigned int)h) << 16);
}

// 16x16x32 bf16 MFMA (validated rounds 1-3 on this op):
// operand frag elem j = M[idx=lane&15][k=(lane>>4)*8+j]; D: col=lane&15 (2nd
// operand idx), row=(lane>>4)*4+reg (1st operand idx).
__device__ __forceinline__ f32x4 MFMA32(s16x8 a, s16x8 b, f32x4 c) {
  return __builtin_amdgcn_mfma_f32_16x16x32_bf16(a, b, c, 0, 0, 0);
}

__device__ __forceinline__ s16x4 pack4(f32x4 v) {
  s16x4 o;
  #pragma unroll
  for (int j = 0; j < 4; j++) o[j] = (short)f2bf(v[j]);
  return o;
}
__device__ __forceinline__ s16x8 pack8(f32x4 a, f32x4 b) {
  s16x8 o;
  #pragma unroll
  for (int j = 0; j < 4; j++) { o[j] = (short)f2bf(a[j]); o[4 + j] = (short)f2bf(b[j]); }
  return o;
}
// swizzled byte offset within [64][512B] LDS row buffers (bijective per row)
__device__ __forceinline__ int msws(int row, int b) {
  return row * 512 + (b ^ ((row & 7) << 4));
}

// ---- repack: sigma-permuted m-side so D slots chain into K=32 B-frags ----
// sigma: m-row m of tile 2G+t  ->  channel G*32 + (m>>2)*8 + t*4 + (m&3)
__global__ void repack_pre(const float* __restrict__ src, char* __restrict__ PW) {
  int g = blockIdx.x * 256 + threadIdx.x;          // 16 frags x 64 lanes
  if (g >= 16 * 64) return;
  int lane = g & 63, f = g >> 6;
  int h = f >> 1, t = f & 1;
  int el = lane & 15, q = lane >> 4;
  int row = h * 32 + (el >> 2) * 8 + t * 4 + (el & 3);
  const float* s = src + (size_t)row * 32 + q * 8;
  s16x8 v;
  #pragma unroll
  for (int i = 0; i < 8; i++) v[i] = (short)f2bf(s[i]);
  *(s16x8*)(PW + (size_t)(h * 42 + t) * 1024 + lane * 16) = v;
}

__global__ void repack_gv(const float* __restrict__ Wg, const float* __restrict__ Wv,
                          char* __restrict__ PW) {
  int g = blockIdx.x * 256 + threadIdx.x;          // 64 frags x 64 lanes
  if (g >= 64 * 64) return;
  int lane = g & 63, f = g >> 6;                   // f = h*8 + j
  int h = f >> 3, j = f & 7;
  int T = 4 * h + (j & 3);
  int G = T >> 1, t = T & 1;
  int el = lane & 15, q = lane >> 4;
  int o = G * 32 + (el >> 2) * 8 + t * 4 + (el & 3);
  const float* s = (j < 4 ? Wg : Wv) + (size_t)o * 32 + q * 8;
  s16x8 v;
  #pragma unroll
  for (int i = 0; i < 8; i++) v[i] = (short)f2bf(s[i]);
  *(s16x8*)(PW + (size_t)(h * 42 + 2 + j) * 1024 + lane * 16) = v;
}

__global__ void repack_post(const float* __restrict__ Wp, char* __restrict__ PW) {
  int g = blockIdx.x * 256 + threadIdx.x;          // 256 frags x 64 lanes
  if (g >= 256 * 64) return;
  int lane = g & 63, f = g >> 6;                   // f = h*32 + c*16 + m
  int h = f >> 5, c = (f >> 4) & 1, m = f & 15;
  int el = lane & 15, q = lane >> 4;
  const float* s = Wp + (size_t)(m * 16 + el) * 512 + (h * 2 + c) * 32 + q * 8;
  s16x8 v;
  #pragma unroll
  for (int i = 0; i < 8; i++) v[i] = (short)f2bf(s[i]);
  *(s16x8*)(PW + (size_t)(h * 42 + 10 + c * 16 + m) * 1024 + lane * 16) = v;
}

__global__ __launch_bounds__(256) void proj_kernel(
    const float* __restrict__ x, const float* __restrict__ w_src,
    const float* __restrict__ w_tgt, unsigned short* __restrict__ x0,
    unsigned short* __restrict__ x1) {
  __shared__ float xs[32 * 256];
  const int tid = threadIdx.x;
  const int row0 = blockIdx.x * 32;
  const float* w = blockIdx.y ? w_tgt : w_src;
  unsigned short* out = blockIdx.y ? x1 : x0;

  const float4* src = (const float4*)(x + (size_t)row0 * CC);
  float4* dstv = (float4*)xs;
  for (int i = tid; i < 2048; i += 256) dstv[i] = src[i];
  __syncthreads();

  const int c = tid;
  float acc[32];
  #pragma unroll
  for (int r = 0; r < 32; r++) acc[r] = 0.f;
  for (int k = 0; k < 256; k += 4) {
    float4 wv = *(const float4*)(w + (size_t)c * CC + k);
    #pragma unroll
    for (int r = 0; r < 32; r++) {
      float4 xv = *(const float4*)(&xs[r * 256 + k]);
      acc[r] += xv.x * wv.x + xv.y * wv.y + xv.z * wv.z + xv.w * wv.w;
    }
  }
  #pragma unroll
  for (int r = 0; r < 32; r++) out[(size_t)(row0 + r) * CC + c] = f2bf(acc[r]);
}

__global__ void deg_int_kernel(const int* __restrict__ ei, int* __restrict__ degi) {
  int e = blockIdx.x * blockDim.x + threadIdx.x;
  if (e >= NE) return;
  int k0 = ei[e], k1 = ei[NE + e];
  if (k0 != k1) atomicAdd(&degi[k1], 1);
}

__global__ __launch_bounds__(64) void prefix_kernel(const int* __restrict__ degi,
                                                    int* __restrict__ starts) {
  int lane = threadIdx.x;
  int runoff = 0;
  for (int base = 0; base < NN; base += 64) {
    int v = (base + lane < NN) ? degi[base + lane] : 0;
    int s = v;
    #pragma unroll
    for (int o = 1; o < 64; o <<= 1) {
      int x = __shfl_up(s, o);
      if (lane >= o) s += x;
    }
    if (base + lane < NN) starts[base + lane] = runoff + s - v;
    runoff += __shfl(s, 63);
  }
  if (lane == 0) starts[NN] = runoff;
}

__global__ void fill_kernel(const int* __restrict__ ei, const int* __restrict__ starts,
                            int* __restrict__ cursor, int* __restrict__ elist) {
  int e = blockIdx.x * blockDim.x + threadIdx.x;
  if (e >= NE) return;
  int k0 = ei[e], k1 = ei[NE + e];
  if (k0 != k1) {
    int p = atomicAdd(&cursor[k1], 1);
    elist[starts[k1] + p] = e;
  }
}

// ---------------- fused edge kernel: LDS-staged weights, K=32 chain --------
// 512 thr = 8 waves = 4 tiles x 2 chalf; 64 CSR slots/block. Weights staged
// per h-step (42KB) into a double-buffered LDS region by all threads; frags
// consumed via ds_read_b128. sigma-permuted repack makes each stage's D
// concat-pack directly into the next K=32 B-frag (zero shuffles).
__global__ __launch_bounds__(512, 2) void edge_fused(
    const unsigned short* __restrict__ x0g, const unsigned short* __restrict__ x1g,
    const float* __restrict__ z_rw, const int* __restrict__ ei,
    const int* __restrict__ elist, const int* __restrict__ starts,
    const char* __restrict__ PWp, const char* __restrict__ PWf,
    unsigned short* __restrict__ MSG) {
  __shared__ char MSb[32768];           // msg rows bf16, swizzled
  __shared__ char BIAS[32768];          // bias rows bf16, swizzled (by channel)
  __shared__ char WS[2 * WSB];          // 84KB weight stage double buffer
  __shared__ float ST[64][20];          // ffn GN stats
  __shared__ int K0s[64], K1s[64];

  const int tid = threadIdx.x;
  const int lane = tid & 63;
  const int w = tid >> 6;
  const int el = lane & 15, q = lane >> 4;
  const int chalf = w & 1;
  const int tp = w >> 1;                // edge tile 0..3
  const int sbase = blockIdx.x * 64;
  const f32x4 zero4 = {0.f, 0.f, 0.f, 0.f};
  const int nv = starts[NN];

  if (tid < 64) {
    int slot = sbase + tid;
    int e = elist[slot < nv ? slot : 0];
    K0s[tid] = ei[e];
    K1s[tid] = ei[NE + e];
  }
  __syncthreads();

  // ---- msg rows -> MSb (+ ffn GN stats). One full 512B row per load. ----
  #pragma unroll 4
  for (int i = 0; i < 8; i++) {
    int row = w * 8 + i;
    s16x4 a = *(const s16x4*)(x0g + (size_t)K0s[row] * 256 + lane * 4);
    s16x4 b = *(const s16x4*)(x1g + (size_t)K1s[row] * 256 + lane * 4);
    f32x4 m;
    #pragma unroll
    for (int j = 0; j < 4; j++)
      m[j] = bf2f((unsigned short)a[j]) + bf2f((unsigned short)b[j]);
    float s1 = m[0] + m[1] + m[2] + m[3];
    float s2 = m[0]*m[0] + m[1]*m[1] + m[2]*m[2] + m[3]*m[3];
    s1 += __shfl_xor(s1, 1); s1 += __shfl_xor(s1, 2); s1 += __shfl_xor(s1, 4);
    s2 += __shfl_xor(s2, 1); s2 += __shfl_xor(s2, 2); s2 += __shfl_xor(s2, 4);
    if ((lane & 7) == 0) {
      float mu = s1 * (1.f / 32.f);
      float var = fmaxf(s2 * (1.f / 32.f) - mu * mu, 0.f);
      ST[row][(lane >> 3) * 2]     = mu;
      ST[row][(lane >> 3) * 2 + 1] = rsqrtf(var + 1e-5f);
    }
    *(s16x4*)(MSb + msws(row, lane * 8)) = pack4(m);
  }

  // ---- z K=32 frag: k 0..15 = z_rw[k0], 16..31 = z_rw[k1] ----
  const int ke0 = K0s[tp * 16 + el];
  const int ke1 = K1s[tp * 16 + el];
  s16x8 bz;
  {
    int node = (q < 2) ? ke0 : ke1;
    const float* zp = z_rw + (size_t)node * 16 + (q & 1) * 8;
    #pragma unroll
    for (int i = 0; i < 8; i++) bz[i] = (short)f2bf(zp[i]);
  }

  // ---- prologue: stage perw h=0 into WS[0] ----
  #pragma unroll
  for (int r = 0; r < 6; r++) {
    int off = r * 8192 + tid * 16;
    if (off < WSB) {
      s16x8 vv = *(const s16x8*)(PWp + off);
      *(s16x8*)(WS + off) = vv;
    }
  }
  __syncthreads();

  f32x4 acc[8];
  #pragma unroll
  for (int c8 = 0; c8 < 8; c8++) acc[c8] = zero4;

  const int row = tp * 16 + el;
  int cur = 0;
  for (int s = 0; s < 16; s++) {
    const int phase = s >> 3, h = s & 7;
    // prefetch next step's weights into regs
    s16x8 streg[6];
    int nlo = 0;
    const char* nsrc = nullptr;
    if (s < 15) {
      int s2 = s + 1, p2 = s2 >> 3, h2 = s2 & 7;
      nlo = (p2 == 0) ? 0 : 2048;
      nsrc = (p2 == 0 ? PWp : PWf) + (size_t)h2 * WSB;
      #pragma unroll
      for (int r = 0; r < 6; r++) {
        int off = nlo + r * 8192 + tid * 16;
        if (off < WSB) streg[r] = *(const s16x8*)(nsrc + off);
      }
    }
    const char* C = WS + cur * WSB;
    #define LDF(idx) (*(const s16x8*)(C + (idx) * 1024 + lane * 16))

    s16x8 tg, tv;
    if (phase == 0) {
      // pre-GEMM (2 MFMA) + GroupNorm in registers
      f32x4 pr0 = MFMA32(LDF(0), bz, zero4);
      f32x4 pr1 = MFMA32(LDF(1), bz, zero4);
      float s1 = 0.f, s2 = 0.f;
      #pragma unroll
      for (int j = 0; j < 4; j++) {
        s1 += pr0[j] + pr1[j];
        s2 += pr0[j] * pr0[j] + pr1[j] * pr1[j];
      }
      s1 += __shfl_xor(s1, 16); s1 += __shfl_xor(s1, 32);
      s2 += __shfl_xor(s2, 16); s2 += __shfl_xor(s2, 32);
      float mu = s1 * (1.f / 32.f);
      float var = fmaxf(s2 * (1.f / 32.f) - mu * mu, 0.f);
      float ri = rsqrtf(var + 1e-5f);
      f32x4 n0, n1;
      #pragma unroll
      for (int j = 0; j < 4; j++) {
        n0[j] = (pr0[j] - mu) * ri;
        n1[j] = (pr1[j] - mu) * ri;
      }
      tg = pack8(n0, n1);
      tv = tg;
    } else {
      // normalized msg (+bias into gate) from LDS
      float mu = ST[row][h * 2], ri = ST[row][h * 2 + 1];
      s16x8 raw = *(const s16x8*)(MSb + msws(row, h * 64 + q * 16));
      s16x8 braw = *(const s16x8*)(BIAS + msws(row, h * 64 + q * 16));
      f32x4 n0, n1, g0, g1;
      #pragma unroll
      for (int j = 0; j < 4; j++) {
        n0[j] = (bf2f((unsigned short)raw[j]) - mu) * ri;
        n1[j] = (bf2f((unsigned short)raw[4 + j]) - mu) * ri;
        g0[j] = n0[j] + bf2f((unsigned short)braw[j]);
        g1[j] = n1[j] + bf2f((unsigned short)braw[4 + j]);
      }
      tv = pack8(n0, n1);
      tg = pack8(g0, g1);
    }
    // gate/value (8 MFMA) + post (16 MFMA)
    #pragma unroll
    for (int c = 0; c < 2; c++) {
      f32x4 g0 = MFMA32(LDF(2 + 2 * c), tg, zero4);
      f32x4 g1 = MFMA32(LDF(3 + 2 * c), tg, zero4);
      f32x4 v0 = MFMA32(LDF(6 + 2 * c), tv, zero4);
      f32x4 v1 = MFMA32(LDF(7 + 2 * c), tv, zero4);
      f32x4 u0, u1;
      #pragma unroll
      for (int j = 0; j < 4; j++) {
        u0[j] = fmaxf(g0[j], 0.f) * v0[j];
        u1[j] = fmaxf(g1[j], 0.f) * v1[j];
      }
      s16x8 u = pack8(u0, u1);
      #pragma unroll
      for (int c8 = 0; c8 < 8; c8++)
        acc[c8] = MFMA32(LDF(10 + c * 16 + chalf * 8 + c8), u, acc[c8]);
    }
    #undef LDF

    // commit prefetched weights to the other buffer
    if (s < 15) {
      #pragma unroll
      for (int r = 0; r < 6; r++) {
        int off = nlo + r * 8192 + tid * 16;
        if (off < WSB) *(s16x8*)(WS + (cur ^ 1) * WSB + off) = streg[r];
      }
    }
    if (s == 7) {
      // perw bias -> BIAS (by natural channel), reset acc
      #pragma unroll
      for (int c8 = 0; c8 < 8; c8++) {
        *(s16x4*)(BIAS + msws(row, chalf * 256 + c8 * 32 + q * 8)) = pack4(acc[c8]);
        acc[c8] = zero4;
      }
    }
    __syncthreads();
    cur ^= 1;
  }

  // ---- transpose acc through MSb, then full-row stores to MSG ----
  #pragma unroll
  for (int c8 = 0; c8 < 8; c8++)
    *(s16x4*)(MSb + msws(row, chalf * 256 + c8 * 32 + q * 8)) = pack4(acc[c8]);
  __syncthreads();
  #pragma unroll 4
  for (int i = 0; i < 8; i++) {
    int r2 = w * 8 + i;
    int slot = sbase + r2;
    if (slot < nv) {
      s16x4 v = *(const s16x4*)(MSb + msws(r2, lane * 8));
      *(s16x4*)(MSG + (size_t)slot * 256 + lane * 4) = v;
    }
  }
}

// per-node aggregation over CONTIGUOUS slots + degree-power + residual
__global__ __launch_bounds__(256) void aggregate_kernel(
    const unsigned short* __restrict__ MSG, const int* __restrict__ starts,
    const float* __restrict__ dp, const float* __restrict__ x_res,
    float* __restrict__ out) {
  int wid = threadIdx.x >> 6, lane = threadIdx.x & 63;
  int n = blockIdx.x * 4 + wid;
  if (n >= NN) return;
  int i0 = starts[n], en = starts[n + 1];
  float a0 = 0.f, a1 = 0.f, a2 = 0.f, a3 = 0.f;
  int i = i0;
  for (; i + 2 <= en; i += 2) {
    s16x4 v0 = *(const s16x4*)(MSG + (size_t)i * 256 + lane * 4);
    s16x4 v1 = *(const s16x4*)(MSG + (size_t)(i + 1) * 256 + lane * 4);
    a0 += bf2f((unsigned short)v0[0]) + bf2f((unsigned short)v1[0]);
    a1 += bf2f((unsigned short)v0[1]) + bf2f((unsigned short)v1[1]);
    a2 += bf2f((unsigned short)v0[2]) + bf2f((unsigned short)v1[2]);
    a3 += bf2f((unsigned short)v0[3]) + bf2f((unsigned short)v1[3]);
  }
  if (i < en) {
    s16x4 v0 = *(const s16x4*)(MSG + (size_t)i * 256 + lane * 4);
    a0 += bf2f((unsigned short)v0[0]);
    a1 += bf2f((unsigned short)v0[1]);
    a2 += bf2f((unsigned short)v0[2]);
    a3 += bf2f((unsigned short)v0[3]);
  }
  int degc = en - i0;
  float d = (float)(degc > 1 ? degc : 1);
  float l2 = __log2f(d);
  float4 dpv = *(const float4*)(dp + lane * 4);
  float4 xr = *(const float4*)(x_res + (size_t)n * CC + lane * 4);
  float4 o;
  o.x = exp2f(l2 * dpv.x) * a0 + xr.x;
  o.y = exp2f(l2 * dpv.y) * a1 + xr.y;
  o.z = exp2f(l2 * dpv.z) * a2 + xr.z;
  o.w = exp2f(l2 * dpv.w) * a3 + xr.w;
  *(float4*)(out + (size_t)n * CC + lane * 4) = o;
}

extern "C" void kernel_launch(void* const* d_in, const int* in_sizes, int n_in,
                              void* d_out, int out_size, void* d_ws, size_t ws_size,
                              hipStream_t stream) {
  (void)in_sizes; (void)n_in; (void)out_size; (void)ws_size;
  const float* x        = (const float*)d_in[0];
  const float* x_res    = (const float*)d_in[1];
  const float* z_rw     = (const float*)d_in[2];
  const int*   ei       = (const int*)d_in[3];
  const float* w_src    = (const float*)d_in[4];
  const float* w_tgt    = (const float*)d_in[5];
  const float* w_pre    = (const float*)d_in[6];
  const float* w_gate_p = (const float*)d_in[7];
  const float* w_val_p  = (const float*)d_in[8];
  const float* w_post_p = (const float*)d_in[9];
  const float* w_gate_f = (const float*)d_in[10];
  const float* w_val_f  = (const float*)d_in[11];
  const float* w_post_f = (const float*)d_in[12];
  const float* dparam   = (const float*)d_in[13];
  float* out = (float*)d_out;

  // ---- workspace layout (256B aligned) ----
  char* W = (char*)d_ws;
  size_t off = 0;
  auto alloc = [&](size_t bytes) {
    size_t o = off;
    off = (off + bytes + 255) & ~(size_t)255;
    return o;
  };
  unsigned short* x0   = (unsigned short*)(W + alloc((size_t)NN * CC * 2));
  unsigned short* x1   = (unsigned short*)(W + alloc((size_t)NN * CC * 2));
  char* PWp            = W + alloc(8 * (size_t)WSB);
  char* PWf            = W + alloc(8 * (size_t)WSB);
  int* degi            = (int*)(W + alloc(2 * (size_t)NN * 4));
  int* cursor          = degi + NN;
  int* starts          = (int*)(W + alloc(((size_t)NN + 1) * 4));
  int* elist           = (int*)(W + alloc((size_t)NE * 4));
  unsigned short* MSG  = (unsigned short*)(W + alloc((size_t)NE * CC * 2));

  hipMemsetAsync(degi, 0, 2 * (size_t)NN * 4, stream);

  repack_pre<<<4, 256, 0, stream>>>(w_pre, PWp);
  repack_gv<<<16, 256, 0, stream>>>(w_gate_p, w_val_p, PWp);
  repack_post<<<64, 256, 0, stream>>>(w_post_p, PWp);
  repack_gv<<<16, 256, 0, stream>>>(w_gate_f, w_val_f, PWf);
  repack_post<<<64, 256, 0, stream>>>(w_post_f, PWf);

  proj_kernel<<<dim3(NN / 32, 2), 256, 0, stream>>>(x, w_src, w_tgt, x0, x1);
  deg_int_kernel<<<(NE + 255) / 256, 256, 0, stream>>>(ei, degi);
  prefix_kernel<<<1, 64, 0, stream>>>(degi, starts);
  fill_kernel<<<(NE + 255) / 256, 256, 0, stream>>>(ei, starts, cursor, elist);

  edge_fused<<<NE / 64, 512, 0, stream>>>(x0, x1, z_rw, ei, elist, starts,
                                          PWp, PWf, MSG);
  aggregate_kernel<<<(NN + 3) / 4, 256, 0, stream>>>(MSG, starts,
                                                     dparam, x_res, out);
}